// Round 1
// baseline (619.652 us; speedup 1.0000x reference)
//
#include <hip/hip_runtime.h>

#define B_  32
#define N_  512
#define D_  512
#define H_  8
#define DH_ 64
#define M_  (B_*N_)   // 16384

typedef __attribute__((ext_vector_type(4))) float          f32x4;
typedef __attribute__((ext_vector_type(8))) unsigned short us8;
typedef __attribute__((ext_vector_type(8))) __bf16         bf16x8;

__device__ __forceinline__ f32x4 mfma_bf16(us8 a, us8 b, f32x4 c) {
  return __builtin_amdgcn_mfma_f32_16x16x32_bf16(
      __builtin_bit_cast(bf16x8, a), __builtin_bit_cast(bf16x8, b), c, 0, 0, 0);
}

__device__ __forceinline__ unsigned short f2bf(float f) {  // RNE f32->bf16
  unsigned int u = __builtin_bit_cast(unsigned int, f);
  u = (u + 0x7FFFu + ((u >> 16) & 1u)) >> 16;
  return (unsigned short)u;
}

__device__ __forceinline__ us8 ldg8(const unsigned short* p) {
  return *reinterpret_cast<const us8*>(p);
}

// ---------------- weight transpose fp32 -> bf16 (Wq,Wk,Wv,Wo) ----------------
__global__ __launch_bounds__(256) void k_transpose_w(
    const float* __restrict__ Wq, const float* __restrict__ Wk,
    const float* __restrict__ Wv, const float* __restrict__ Wo,
    unsigned short* __restrict__ wT) {
  __shared__ float t[32][33];
  int z = blockIdx.z;
  const float* W = (z == 0) ? Wq : (z == 1) ? Wk : (z == 2) ? Wv : Wo;
  unsigned short* out = wT + (size_t)z * (D_ * D_);
  int c0 = blockIdx.x * 32, r0 = blockIdx.y * 32;
  int tx = threadIdx.x, ty = threadIdx.y;
  for (int yy = ty; yy < 32; yy += 8)
    t[yy][tx] = W[(r0 + yy) * D_ + c0 + tx];
  __syncthreads();
  for (int yy = ty; yy < 32; yy += 8)
    out[(c0 + yy) * D_ + r0 + tx] = f2bf(t[tx][yy]);
}

// ---------------- embed: h[m][d] = x[m]*W_emb[n][d] + b_emb[n][d] ----------------
__global__ __launch_bounds__(256) void k_embed(
    const float* __restrict__ x, const float* __restrict__ W_emb,
    const float* __restrict__ b_emb, unsigned short* __restrict__ hbf) {
  int m = blockIdx.x;
  int n = m & (N_ - 1);
  float xv = x[m];
  const float* wr = W_emb + n * D_;
  const float* br = b_emb + n * D_;
  for (int d = threadIdx.x; d < D_; d += 256)
    hbf[(size_t)m * D_ + d] = f2bf(xv * wr[d] + br[d]);
}

// ---------------- QKV GEMM: [16384,512]@[512,512] x3, MFMA 16x16x32 ----------------
// z=0 -> q [B,H,N,DH]; z=1 -> k [B,H,N,DH]; z=2 -> v stored transposed [B,H,DH,N]
__global__ __launch_bounds__(256, 4) void k_qkv(
    const unsigned short* __restrict__ hbf, const unsigned short* __restrict__ wT,
    const float* __restrict__ bq, const float* __restrict__ bk, const float* __restrict__ bv,
    unsigned short* __restrict__ q, unsigned short* __restrict__ k,
    unsigned short* __restrict__ vT) {
  int z = blockIdx.z;
  const unsigned short* w = wT + (size_t)z * (D_ * D_);
  const float* bias = (z == 0) ? bq : (z == 1) ? bk : bv;
  int tile_m = blockIdx.y * 64;
  int wave = threadIdx.x >> 6, lane = threadIdx.x & 63;
  int lrow = lane & 15, g = lane >> 4;
  int j = blockIdx.x * 64 + wave * 16 + lrow;     // output column
  f32x4 acc[4];
#pragma unroll
  for (int i = 0; i < 4; ++i) acc[i] = (f32x4){0.f, 0.f, 0.f, 0.f};
  const unsigned short* wrow = w + (size_t)j * D_;
#pragma unroll 4
  for (int ks = 0; ks < 16; ++ks) {
    int k0 = ks * 32 + g * 8;
    us8 bfrag = ldg8(wrow + k0);
#pragma unroll
    for (int rb = 0; rb < 4; ++rb) {
      us8 afrag = ldg8(hbf + (size_t)(tile_m + rb * 16 + lrow) * D_ + k0);
      acc[rb] = mfma_bf16(afrag, bfrag, acc[rb]);
    }
  }
  float bj = bias[j];
  int head = j >> 6, dh = j & 63;
#pragma unroll
  for (int rb = 0; rb < 4; ++rb) {
#pragma unroll
    for (int r = 0; r < 4; ++r) {
      int m = tile_m + rb * 16 + g * 4 + r;
      int b = m >> 9, n = m & (N_ - 1);
      unsigned short v16 = f2bf(acc[rb][r] + bj);
      if (z == 0)      q [((size_t)(b * H_ + head) * N_ + n) * DH_ + dh] = v16;
      else if (z == 1) k [((size_t)(b * H_ + head) * N_ + n) * DH_ + dh] = v16;
      else             vT[((size_t)(b * H_ + head) * DH_ + dh) * N_ + n] = v16;
    }
  }
}

// ---------------- attention per (b,h): S^T = mfma(K,Q); softmax over m; O^T = mfma(vT,P^T) ----------------
__global__ __launch_bounds__(256, 2) void k_attn(
    const unsigned short* __restrict__ q, const unsigned short* __restrict__ kk,
    const unsigned short* __restrict__ vT, unsigned short* __restrict__ o) {
  __shared__ __align__(16) unsigned short plds[4][16 * 512];  // per-wave P^T [n=16][m=512], XOR-swizzled
  int nhalf = blockIdx.x, bh = blockIdx.y;
  int b = bh >> 3, h = bh & 7;
  const unsigned short* qh = q  + (size_t)bh * (N_ * DH_);
  const unsigned short* kh = kk + (size_t)bh * (N_ * DH_);
  const unsigned short* vh = vT + (size_t)bh * (DH_ * N_);
  int wave = threadIdx.x >> 6, lane = threadIdx.x & 63;
  int lrow = lane & 15, g = lane >> 4;
  char* plw = (char*)&plds[wave][0];
  const float cexp = 0.18033688011112042f;  // log2(e)/8  (1/sqrt(DH) fold)

  for (int t = 0; t < 4; ++t) {
    int n0 = nhalf * 256 + wave * 64 + t * 16;
    const unsigned short* qrow = qh + (size_t)(n0 + lrow) * DH_;
    us8 bq0 = ldg8(qrow + g * 8);          // B-frag: q^T, k-chunk dh 0..31
    us8 bq1 = ldg8(qrow + 32 + g * 8);     // dh 32..63
    f32x4 s[32];                            // S^T[m][n]: col n = lane&15, rows m lane-local
#pragma unroll
    for (int mc = 0; mc < 32; ++mc) {
      const unsigned short* krow = kh + (size_t)(mc * 16 + lrow) * DH_;
      f32x4 a = (f32x4){0.f, 0.f, 0.f, 0.f};
      a = mfma_bf16(ldg8(krow + g * 8), bq0, a);
      a = mfma_bf16(ldg8(krow + 32 + g * 8), bq1, a);
      s[mc] = a;
    }
    // wave-parallel softmax over m (512) for this lane's column n
    float mx = -3.0e38f;
#pragma unroll
    for (int mc = 0; mc < 32; ++mc)
      mx = fmaxf(fmaxf(fmaxf(mx, s[mc][0]), fmaxf(s[mc][1], s[mc][2])), s[mc][3]);
    mx = fmaxf(mx, __shfl_xor(mx, 16, 64));
    mx = fmaxf(mx, __shfl_xor(mx, 32, 64));
    float sum = 0.f;
#pragma unroll
    for (int mc = 0; mc < 32; ++mc) {
#pragma unroll
      for (int r = 0; r < 4; ++r) {
        float p = exp2f((s[mc][r] - mx) * cexp);
        s[mc][r] = p;
        sum += p;
      }
    }
    sum += __shfl_xor(sum, 16, 64);
    sum += __shfl_xor(sum, 32, 64);
    float inv = 1.f / sum;   // applied at O epilogue (same lane column)
    // P^T (unnormalized, <=1) -> LDS bf16, [n][m] with XOR swizzle on byte bit4
#pragma unroll
    for (int mc = 0; mc < 32; ++mc) {
      unsigned int w0 = (unsigned)f2bf(s[mc][0]) | ((unsigned)f2bf(s[mc][1]) << 16);
      unsigned int w1 = (unsigned)f2bf(s[mc][2]) | ((unsigned)f2bf(s[mc][3]) << 16);
      unsigned off = (unsigned)((lrow * 1024 + (mc * 16 + g * 4) * 2) ^ ((lrow & 7) << 4));
      *reinterpret_cast<uint2*>(plw + off) = make_uint2(w0, w1);
    }
    // O^T[dh][n] = sum_m vT[dh][m] * P^T[m][n]
    f32x4 oacc[4];
#pragma unroll
    for (int i = 0; i < 4; ++i) oacc[i] = (f32x4){0.f, 0.f, 0.f, 0.f};
#pragma unroll 4
    for (int mb = 0; mb < 16; ++mb) {
      int m0 = mb * 32 + g * 8;
      unsigned off = (unsigned)((lrow * 1024 + m0 * 2) ^ ((lrow & 7) << 4));
      us8 bp = *reinterpret_cast<const us8*>(plw + off);
#pragma unroll
      for (int db = 0; db < 4; ++db) {
        us8 av = ldg8(vh + (size_t)(db * 16 + lrow) * N_ + m0);
        oacc[db] = mfma_bf16(av, bp, oacc[db]);
      }
    }
    int n = n0 + lrow;
#pragma unroll
    for (int db = 0; db < 4; ++db) {
#pragma unroll
      for (int r = 0; r < 4; ++r) {
        int dh = db * 16 + g * 4 + r;
        o[((size_t)(b * N_ + n)) * D_ + h * DH_ + dh] = f2bf(oacc[db][r] * inv);
      }
    }
  }
}

// ---------------- o @ Wo + bo -> fp32 [16384,512] ----------------
__global__ __launch_bounds__(256, 4) void k_wo(
    const unsigned short* __restrict__ obf, const unsigned short* __restrict__ woT,
    const float* __restrict__ bo, float* __restrict__ oWo) {
  int tile_m = blockIdx.y * 64;
  int wave = threadIdx.x >> 6, lane = threadIdx.x & 63;
  int lrow = lane & 15, g = lane >> 4;
  int j = blockIdx.x * 64 + wave * 16 + lrow;
  f32x4 acc[4];
#pragma unroll
  for (int i = 0; i < 4; ++i) acc[i] = (f32x4){0.f, 0.f, 0.f, 0.f};
  const unsigned short* wrow = woT + (size_t)j * D_;
#pragma unroll 4
  for (int ks = 0; ks < 16; ++ks) {
    int k0 = ks * 32 + g * 8;
    us8 bfrag = ldg8(wrow + k0);
#pragma unroll
    for (int rb = 0; rb < 4; ++rb) {
      us8 afrag = ldg8(obf + (size_t)(tile_m + rb * 16 + lrow) * D_ + k0);
      acc[rb] = mfma_bf16(afrag, bfrag, acc[rb]);
    }
  }
  float bj = bo[j];
#pragma unroll
  for (int rb = 0; rb < 4; ++rb)
#pragma unroll
    for (int r = 0; r < 4; ++r) {
      int m = tile_m + rb * 16 + g * 4 + r;
      oWo[(size_t)m * D_ + j] = acc[rb][r] + bj;
    }
}

// ---------------- unembed: x_atten[m] = dot(oWo[m,:], W_un[n,:]) + b_un[n] ----------------
__global__ __launch_bounds__(256) void k_unembed(
    const float* __restrict__ oWo, const float* __restrict__ Wun,
    const float* __restrict__ bun, float* __restrict__ xa, float* __restrict__ out_xa) {
  int m = blockIdx.x * 4 + (threadIdx.x >> 6);
  int lane = threadIdx.x & 63;
  int n = m & (N_ - 1);
  const f32x4* a = reinterpret_cast<const f32x4*>(oWo + (size_t)m * D_);
  const f32x4* w = reinterpret_cast<const f32x4*>(Wun + (size_t)n * D_);
  f32x4 av0 = a[lane],      wv0 = w[lane];
  f32x4 av1 = a[lane + 64], wv1 = w[lane + 64];
  float s = av0[0]*wv0[0] + av0[1]*wv0[1] + av0[2]*wv0[2] + av0[3]*wv0[3]
          + av1[0]*wv1[0] + av1[1]*wv1[1] + av1[2]*wv1[2] + av1[3]*wv1[3];
#pragma unroll
  for (int off = 32; off; off >>= 1) s += __shfl_xor(s, off, 64);
  if (lane == 0) {
    float v = s + bun[n];
    xa[m] = v;
    out_xa[m] = v;
  }
}

// ---------------- ff stages (small, fp32, coalesced weight columns) ----------------
__global__ __launch_bounds__(256) void k_ff1(
    const float* __restrict__ xa, const float* __restrict__ W1,
    const float* __restrict__ b1, float* __restrict__ y1) {
  int gid = blockIdx.x * 256 + threadIdx.x;   // 65536
  int c = gid & 2047, b = gid >> 11;
  const float* xr = xa + b * N_;
  float s = b1[c];
#pragma unroll 8
  for (int n = 0; n < 512; ++n) s = fmaf(xr[n], W1[(size_t)n * 2048 + c], s);
  y1[(size_t)b * 2048 + c] = s;
}

__global__ __launch_bounds__(256) void k_ff2(
    const float* __restrict__ y1, const float* __restrict__ W2,
    const float* __restrict__ b2, float* __restrict__ y2) {
  int gid = blockIdx.x * 256 + threadIdx.x;   // 16384
  int c = gid & 511, b = gid >> 9;
  const float* xr = y1 + (size_t)b * 2048;
  float s = b2[c];
#pragma unroll 8
  for (int n = 0; n < 2048; ++n) s = fmaf(xr[n], W2[(size_t)n * 512 + c], s);
  y2[(size_t)b * 512 + c] = s;
}

// ---------------- ff3 + bilinear upsample 8x32 -> 16x64 + min-max norm ----------------
__global__ __launch_bounds__(256) void k_ff3_up(
    const float* __restrict__ y2, const float* __restrict__ W3,
    const float* __restrict__ b3, float* __restrict__ out) {
  __shared__ float y3[256];
  __shared__ float red[8];
  int b = blockIdx.x, t = threadIdx.x;
  const float* yr = y2 + (size_t)b * 512;
  float s = b3[t];
  for (int d = 0; d < 512; ++d) s = fmaf(yr[d], W3[(size_t)d * 256 + t], s);
  y3[t] = s;
  __syncthreads();
  float vals[4];
  float mn = 3.0e38f, mx = -3.0e38f;
#pragma unroll
  for (int p2 = 0; p2 < 4; ++p2) {
    int p = t * 4 + p2;
    int i = p >> 6, jj = p & 63;
    float sy = fmaxf((float)i * 0.5f - 0.25f, 0.0f);
    int y0 = (int)sy; float fy = sy - (float)y0;
    int y1i = min(y0 + 1, 7);
    float sx = fmaxf((float)jj * 0.5f - 0.25f, 0.0f);
    int x0 = (int)sx; float fx = sx - (float)x0;
    int x1 = min(x0 + 1, 31);
    float v00 = y3[y0 * 32 + x0], v01 = y3[y0 * 32 + x1];
    float v10 = y3[y1i * 32 + x0], v11 = y3[y1i * 32 + x1];
    float v = (1.f - fy) * ((1.f - fx) * v00 + fx * v01)
            +        fy  * ((1.f - fx) * v10 + fx * v11);
    vals[p2] = v;
    mn = fminf(mn, v); mx = fmaxf(mx, v);
  }
#pragma unroll
  for (int off = 32; off; off >>= 1) {
    mn = fminf(mn, __shfl_xor(mn, off, 64));
    mx = fmaxf(mx, __shfl_xor(mx, off, 64));
  }
  int wv = t >> 6;
  if ((t & 63) == 0) { red[wv] = mn; red[4 + wv] = mx; }
  __syncthreads();
  mn = fminf(fminf(red[0], red[1]), fminf(red[2], red[3]));
  mx = fmaxf(fmaxf(red[4], red[5]), fmaxf(red[6], red[7]));
  float inv = 1.f / (mx - mn + 1e-8f);
#pragma unroll
  for (int p2 = 0; p2 < 4; ++p2)
    out[(size_t)b * 1024 + t * 4 + p2] = (vals[p2] - mn) * inv;
}

// ---------------- launch ----------------
extern "C" void kernel_launch(void* const* d_in, const int* in_sizes, int n_in,
                              void* d_out, int out_size, void* d_ws, size_t ws_size,
                              hipStream_t stream) {
  const float* x     = (const float*)d_in[0];
  const float* W_emb = (const float*)d_in[1];
  const float* b_emb = (const float*)d_in[2];
  const float* Wq    = (const float*)d_in[3];
  const float* bq    = (const float*)d_in[4];
  const float* Wk    = (const float*)d_in[5];
  const float* bk    = (const float*)d_in[6];
  const float* Wv    = (const float*)d_in[7];
  const float* bv    = (const float*)d_in[8];
  const float* Wo    = (const float*)d_in[9];
  const float* bo    = (const float*)d_in[10];
  const float* W_un  = (const float*)d_in[11];
  const float* b_un  = (const float*)d_in[12];
  const float* W1    = (const float*)d_in[13];
  const float* b1    = (const float*)d_in[14];
  const float* W2    = (const float*)d_in[15];
  const float* b2    = (const float*)d_in[16];
  const float* W3    = (const float*)d_in[17];
  const float* b3    = (const float*)d_in[18];

  char* ws = (char*)d_ws;
  // layout (bytes): h/o bf16 16M | q 16M | k 16M | vT 16M | wT 2M | xa | y1 | y2
  unsigned short* hbf = (unsigned short*)(ws + 0);            // also reused as o
  unsigned short* q   = (unsigned short*)(ws + 16777216);
  unsigned short* k   = (unsigned short*)(ws + 33554432);
  unsigned short* vT  = (unsigned short*)(ws + 50331648);
  unsigned short* wT  = (unsigned short*)(ws + 67108864);     // [Wq^T,Wk^T,Wv^T,Wo^T] bf16
  float* xa  = (float*)(ws + 69206016);
  float* y1  = (float*)(ws + 69271552);
  float* y2  = (float*)(ws + 69533696);
  float* oWo = (float*)(ws + 16777216);                       // reuses q+k (dead after attn)

  float* out_y  = (float*)d_out;            // [32,1,16,64]
  float* out_xa = ((float*)d_out) + 32768;  // [32,512,1]

  k_transpose_w<<<dim3(16, 16, 4), dim3(32, 8), 0, stream>>>(Wq, Wk, Wv, Wo, wT);
  k_embed<<<dim3(M_), dim3(256), 0, stream>>>(x, W_emb, b_emb, hbf);
  k_qkv<<<dim3(8, 256, 3), dim3(256), 0, stream>>>(hbf, wT, bq, bk, bv, q, k, vT);
  k_attn<<<dim3(2, 256), dim3(256), 0, stream>>>(q, k, vT, hbf /* o reuses h */);
  k_wo<<<dim3(8, 256), dim3(256), 0, stream>>>(hbf, wT + 3 * (D_ * D_), bo, oWo);
  k_unembed<<<dim3(M_ / 4), dim3(256), 0, stream>>>(oWo, W_un, b_un, xa, out_xa);
  k_ff1<<<dim3(256), dim3(256), 0, stream>>>(xa, W1, b1, y1);
  k_ff2<<<dim3(64), dim3(256), 0, stream>>>(y1, W2, b2, y2);
  k_ff3_up<<<dim3(B_), dim3(256), 0, stream>>>(y2, W3, b3, out_y);
}

// Round 2
// 318.215 us; speedup vs baseline: 1.9473x; 1.9473x over previous
//
#include <hip/hip_runtime.h>

#define B_  32
#define N_  512
#define D_  512
#define H_  8
#define DH_ 64
#define M_  (B_*N_)   // 16384

typedef __attribute__((ext_vector_type(4))) float          f32x4;
typedef __attribute__((ext_vector_type(8))) unsigned short us8;
typedef __attribute__((ext_vector_type(8))) __bf16         bf16x8;

__device__ __forceinline__ f32x4 mfma_bf16(us8 a, us8 b, f32x4 c) {
  return __builtin_amdgcn_mfma_f32_16x16x32_bf16(
      __builtin_bit_cast(bf16x8, a), __builtin_bit_cast(bf16x8, b), c, 0, 0, 0);
}

__device__ __forceinline__ unsigned short f2bf(float f) {  // RNE f32->bf16
  unsigned int u = __builtin_bit_cast(unsigned int, f);
  u = (u + 0x7FFFu + ((u >> 16) & 1u)) >> 16;
  return (unsigned short)u;
}

__device__ __forceinline__ us8 ldg8(const unsigned short* p) {
  return *reinterpret_cast<const us8*>(p);
}

typedef const unsigned int __attribute__((address_space(1)))* gas_ptr;
typedef unsigned int __attribute__((address_space(3)))* las_ptr;

__device__ __forceinline__ void gload16(const unsigned short* src, unsigned short* ldsdst) {
  __builtin_amdgcn_global_load_lds((gas_ptr)(const void*)src, (las_ptr)(void*)ldsdst, 16, 0, 0);
}

// ---------------- generic transpose fp32 [R][C] -> bf16 [C][R] ----------------
__global__ __launch_bounds__(256) void k_transpose(
    const float* __restrict__ src, unsigned short* __restrict__ dst, int R, int C) {
  __shared__ float t[32][33];
  int c0 = blockIdx.x * 32, r0 = blockIdx.y * 32;
  int tx = threadIdx.x, ty = threadIdx.y;
  for (int yy = ty; yy < 32; yy += 8)
    t[yy][tx] = src[(size_t)(r0 + yy) * C + c0 + tx];
  __syncthreads();
  for (int yy = ty; yy < 32; yy += 8)
    dst[(size_t)(c0 + yy) * R + r0 + tx] = f2bf(t[tx][yy]);
}

// ---------------- embed: h[m][d] = x[m]*W_emb[n][d] + b_emb[n][d] ----------------
__global__ __launch_bounds__(256) void k_embed(
    const float* __restrict__ x, const float* __restrict__ W_emb,
    const float* __restrict__ b_emb, unsigned short* __restrict__ hbf) {
  int m = blockIdx.x;
  int n = m & (N_ - 1);
  float xv = x[m];
  const float* wr = W_emb + n * D_;
  const float* br = b_emb + n * D_;
  for (int d = threadIdx.x; d < D_; d += 256)
    hbf[(size_t)m * D_ + d] = f2bf(xv * wr[d] + br[d]);
}

// ---------------- 128x128x64 LDS-staged MFMA GEMM (m97 structure) ----------------
// EPI=0: fused QKV epilogue (j in [0,1536): q / k / vT writes)
// EPI=1: Wo epilogue + fused unembed partial-dot -> atomicAdd(xa)
template<int EPI>
__global__ __launch_bounds__(256, 2) void k_mm128(
    const unsigned short* __restrict__ A,   // [16384][512] bf16
    const unsigned short* __restrict__ Bt,  // [N][512] bf16 (row j = output col j)
    const float* __restrict__ bias0, const float* __restrict__ bias1,
    const float* __restrict__ bias2,
    const float* __restrict__ Wun,          // EPI=1: [512][512] fp32
    unsigned short* __restrict__ o0, unsigned short* __restrict__ o1,
    unsigned short* __restrict__ o2,
    float* __restrict__ xa,                 // EPI=1: [16384] fp32 (pre-zeroed)
    int ntiles) {
  __shared__ __align__(16) unsigned short lds[2][2 * 128 * 64];
  const int K = 512;
  int nwg = gridDim.x;
  int cpx = nwg >> 3;                                   // nwg % 8 == 0
  int wgid = ((int)blockIdx.x & 7) * cpx + ((int)blockIdx.x >> 3);
  int mt = wgid / ntiles, nt = wgid - mt * ntiles;
  int m0 = mt * 128, n0 = nt * 128;
  int tid = threadIdx.x, wave = tid >> 6, lane = tid & 63;
  int lrow = lane & 15, g = lane >> 4;
  int wr = wave >> 1, wc = wave & 1;

  f32x4 acc[4][4];
#pragma unroll
  for (int i = 0; i < 4; ++i)
#pragma unroll
    for (int j = 0; j < 4; ++j) acc[i][j] = (f32x4){0.f, 0.f, 0.f, 0.f};

  int rseg_base = wave * 8 + (lane >> 3);   // +16 rows per i
  int coff = (lane & 7) * 8;

  // prologue stage buf0, k0=0
#pragma unroll
  for (int i = 0; i < 4; ++i) {
    int rs = i * 32 + rseg_base;            // (i*4+wave)*8 + lane>>3
    gload16(A  + (size_t)(m0 + rs) * K + coff, &lds[0][(i * 4 + wave) * 512]);
    gload16(Bt + (size_t)(n0 + rs) * K + coff, &lds[0][128 * 64 + (i * 4 + wave) * 512]);
  }
  __syncthreads();

  for (int ks = 0; ks < 8; ++ks) {
    if (ks < 7) {
      int k0 = (ks + 1) * 64;
      int buf = (ks + 1) & 1;
#pragma unroll
      for (int i = 0; i < 4; ++i) {
        int rs = i * 32 + rseg_base;
        gload16(A  + (size_t)(m0 + rs) * K + k0 + coff, &lds[buf][(i * 4 + wave) * 512]);
        gload16(Bt + (size_t)(n0 + rs) * K + k0 + coff, &lds[buf][128 * 64 + (i * 4 + wave) * 512]);
      }
    }
    const unsigned short* la = &lds[ks & 1][0];
    const unsigned short* lb = la + 128 * 64;
#pragma unroll
    for (int kk = 0; kk < 2; ++kk) {
      us8 aF[4], bF[4];
#pragma unroll
      for (int mi = 0; mi < 4; ++mi)
        aF[mi] = *reinterpret_cast<const us8*>(la + (wr * 64 + mi * 16 + lrow) * 64 + kk * 32 + g * 8);
#pragma unroll
      for (int ni = 0; ni < 4; ++ni)
        bF[ni] = *reinterpret_cast<const us8*>(lb + (wc * 64 + ni * 16 + lrow) * 64 + kk * 32 + g * 8);
#pragma unroll
      for (int mi = 0; mi < 4; ++mi)
#pragma unroll
        for (int ni = 0; ni < 4; ++ni)
          acc[mi][ni] = mfma_bf16(aF[mi], bF[ni], acc[mi][ni]);
    }
    __syncthreads();
  }

  if (EPI == 0) {
    // fused QKV writes
#pragma unroll
    for (int ni = 0; ni < 4; ++ni) {
      int j = n0 + wc * 64 + ni * 16 + lrow;
      int which = j >> 9, jj = j & 511, head = jj >> 6, dh = jj & 63;
      float bj = (which == 0 ? bias0 : which == 1 ? bias1 : bias2)[jj];
      unsigned short* base = (which == 0) ? o0 : (which == 1) ? o1 : o2;
#pragma unroll
      for (int mi = 0; mi < 4; ++mi) {
#pragma unroll
        for (int r = 0; r < 4; ++r) {
          int m = m0 + wr * 64 + mi * 16 + g * 4 + r;
          int b = m >> 9, n = m & 511;
          unsigned short v = f2bf(acc[mi][ni][r] + bj);
          if (which < 2) base[((size_t)(b * 8 + head) * 512 + n) * 64 + dh] = v;
          else           base[((size_t)(b * 8 + head) * 64 + dh) * 512 + n] = v;
        }
      }
    }
  } else {
    // Wo + fused unembed: xa[m] += sum_j (acc + bo[j]) * Wun[n][j]
    float part[16];
#pragma unroll
    for (int i = 0; i < 16; ++i) part[i] = 0.f;
#pragma unroll
    for (int ni = 0; ni < 4; ++ni) {
      int j = n0 + wc * 64 + ni * 16 + lrow;
      float bj = bias0[j];
#pragma unroll
      for (int mi = 0; mi < 4; ++mi) {
#pragma unroll
        for (int r = 0; r < 4; ++r) {
          int m = m0 + wr * 64 + mi * 16 + g * 4 + r;
          int n = m & 511;
          part[mi * 4 + r] += (acc[mi][ni][r] + bj) * Wun[(size_t)n * 512 + j];
        }
      }
    }
#pragma unroll
    for (int off = 1; off < 16; off <<= 1)
#pragma unroll
      for (int t2 = 0; t2 < 16; ++t2)
        part[t2] += __shfl_xor(part[t2], off, 64);
    if (lrow == 0) {
#pragma unroll
      for (int mi = 0; mi < 4; ++mi)
#pragma unroll
        for (int r = 0; r < 4; ++r)
          atomicAdd(&xa[m0 + wr * 64 + mi * 16 + g * 4 + r], part[mi * 4 + r]);
    }
  }
}

// ---------------- attention (unchanged from round 1, passing) ----------------
__global__ __launch_bounds__(256, 2) void k_attn(
    const unsigned short* __restrict__ q, const unsigned short* __restrict__ kk,
    const unsigned short* __restrict__ vT, unsigned short* __restrict__ o) {
  __shared__ __align__(16) unsigned short plds[4][16 * 512];
  int nhalf = blockIdx.x, bh = blockIdx.y;
  int b = bh >> 3, h = bh & 7;
  const unsigned short* qh = q  + (size_t)bh * (N_ * DH_);
  const unsigned short* kh = kk + (size_t)bh * (N_ * DH_);
  const unsigned short* vh = vT + (size_t)bh * (DH_ * N_);
  int wave = threadIdx.x >> 6, lane = threadIdx.x & 63;
  int lrow = lane & 15, g = lane >> 4;
  char* plw = (char*)&plds[wave][0];
  const float cexp = 0.18033688011112042f;  // log2(e)/8

  for (int t = 0; t < 4; ++t) {
    int n0 = nhalf * 256 + wave * 64 + t * 16;
    const unsigned short* qrow = qh + (size_t)(n0 + lrow) * DH_;
    us8 bq0 = ldg8(qrow + g * 8);
    us8 bq1 = ldg8(qrow + 32 + g * 8);
    f32x4 s[32];
#pragma unroll
    for (int mc = 0; mc < 32; ++mc) {
      const unsigned short* krow = kh + (size_t)(mc * 16 + lrow) * DH_;
      f32x4 a = (f32x4){0.f, 0.f, 0.f, 0.f};
      a = mfma_bf16(ldg8(krow + g * 8), bq0, a);
      a = mfma_bf16(ldg8(krow + 32 + g * 8), bq1, a);
      s[mc] = a;
    }
    float mx = -3.0e38f;
#pragma unroll
    for (int mc = 0; mc < 32; ++mc)
      mx = fmaxf(fmaxf(fmaxf(mx, s[mc][0]), fmaxf(s[mc][1], s[mc][2])), s[mc][3]);
    mx = fmaxf(mx, __shfl_xor(mx, 16, 64));
    mx = fmaxf(mx, __shfl_xor(mx, 32, 64));
    float sum = 0.f;
#pragma unroll
    for (int mc = 0; mc < 32; ++mc) {
#pragma unroll
      for (int r = 0; r < 4; ++r) {
        float p = exp2f((s[mc][r] - mx) * cexp);
        s[mc][r] = p;
        sum += p;
      }
    }
    sum += __shfl_xor(sum, 16, 64);
    sum += __shfl_xor(sum, 32, 64);
    float inv = 1.f / sum;
#pragma unroll
    for (int mc = 0; mc < 32; ++mc) {
      unsigned int w0 = (unsigned)f2bf(s[mc][0]) | ((unsigned)f2bf(s[mc][1]) << 16);
      unsigned int w1 = (unsigned)f2bf(s[mc][2]) | ((unsigned)f2bf(s[mc][3]) << 16);
      unsigned off = (unsigned)((lrow * 1024 + (mc * 16 + g * 4) * 2) ^ ((lrow & 7) << 4));
      *reinterpret_cast<uint2*>(plw + off) = make_uint2(w0, w1);
    }
    f32x4 oacc[4];
#pragma unroll
    for (int i = 0; i < 4; ++i) oacc[i] = (f32x4){0.f, 0.f, 0.f, 0.f};
#pragma unroll 4
    for (int mb = 0; mb < 16; ++mb) {
      int m0 = mb * 32 + g * 8;
      unsigned off = (unsigned)((lrow * 1024 + m0 * 2) ^ ((lrow & 7) << 4));
      us8 bp = *reinterpret_cast<const us8*>(plw + off);
#pragma unroll
      for (int db = 0; db < 4; ++db) {
        us8 av = ldg8(vh + (size_t)(db * 16 + lrow) * N_ + m0);
        oacc[db] = mfma_bf16(av, bp, oacc[db]);
      }
    }
    int n = n0 + lrow;
#pragma unroll
    for (int db = 0; db < 4; ++db) {
#pragma unroll
      for (int r = 0; r < 4; ++r) {
        int dh = db * 16 + g * 4 + r;
        o[((size_t)(b * N_ + n)) * D_ + h * DH_ + dh] = f2bf(oacc[db][r] * inv);
      }
    }
  }
}

// ---------------- zero xa ----------------
__global__ __launch_bounds__(256) void k_zero(float* __restrict__ p) {
  p[blockIdx.x * 256 + threadIdx.x] = 0.f;
}

// ---------------- xa finish: +b_un, write out_xa fp32 + xabf ----------------
__global__ __launch_bounds__(256) void k_xa_fin(
    const float* __restrict__ xa, const float* __restrict__ bun,
    float* __restrict__ out_xa, unsigned short* __restrict__ xabf) {
  int m = blockIdx.x * 256 + threadIdx.x;
  float v = xa[m] + bun[m & (N_ - 1)];
  out_xa[m] = v;
  xabf[m] = f2bf(v);
}

// ---------------- small M=32 MFMA GEMM for ff layers ----------------
__global__ __launch_bounds__(256) void k_ffmm(
    const unsigned short* __restrict__ A,   // [32][K] bf16
    const unsigned short* __restrict__ Bt,  // [N][K] bf16
    const float* __restrict__ bias, int K, int N, int outbf,
    unsigned short* __restrict__ obf, float* __restrict__ of) {
  int wave = threadIdx.x >> 6, lane = threadIdx.x & 63;
  int lrow = lane & 15, g = lane >> 4;
  int j = blockIdx.x * 64 + wave * 16 + lrow;
  f32x4 acc0 = (f32x4){0.f, 0.f, 0.f, 0.f}, acc1 = acc0;
  const unsigned short* brow = Bt + (size_t)j * K;
  for (int k0 = g * 8; k0 < K; k0 += 32) {
    us8 bfr = ldg8(brow + k0);
    acc0 = mfma_bf16(ldg8(A + (size_t)lrow * K + k0), bfr, acc0);
    acc1 = mfma_bf16(ldg8(A + (size_t)(16 + lrow) * K + k0), bfr, acc1);
  }
  float bj = bias[j];
#pragma unroll
  for (int r = 0; r < 4; ++r) {
    int mA = g * 4 + r, mB = 16 + g * 4 + r;
    float vA = acc0[r] + bj, vB = acc1[r] + bj;
    if (outbf) {
      obf[(size_t)mA * N + j] = f2bf(vA);
      obf[(size_t)mB * N + j] = f2bf(vB);
    } else {
      of[(size_t)mA * N + j] = vA;
      of[(size_t)mB * N + j] = vB;
    }
  }
}

// ---------------- bilinear upsample 8x32 -> 16x64 + min-max norm ----------------
__global__ __launch_bounds__(256) void k_up(
    const float* __restrict__ y3g, float* __restrict__ out) {
  __shared__ float y3[256];
  __shared__ float red[8];
  int b = blockIdx.x, t = threadIdx.x;
  y3[t] = y3g[(size_t)b * 256 + t];
  __syncthreads();
  float vals[4];
  float mn = 3.0e38f, mx = -3.0e38f;
#pragma unroll
  for (int p2 = 0; p2 < 4; ++p2) {
    int p = t * 4 + p2;
    int i = p >> 6, jj = p & 63;
    float sy = fmaxf((float)i * 0.5f - 0.25f, 0.0f);
    int y0 = (int)sy; float fy = sy - (float)y0;
    int y1i = min(y0 + 1, 7);
    float sx = fmaxf((float)jj * 0.5f - 0.25f, 0.0f);
    int x0 = (int)sx; float fx = sx - (float)x0;
    int x1 = min(x0 + 1, 31);
    float v00 = y3[y0 * 32 + x0], v01 = y3[y0 * 32 + x1];
    float v10 = y3[y1i * 32 + x0], v11 = y3[y1i * 32 + x1];
    float v = (1.f - fy) * ((1.f - fx) * v00 + fx * v01)
            +        fy  * ((1.f - fx) * v10 + fx * v11);
    vals[p2] = v;
    mn = fminf(mn, v); mx = fmaxf(mx, v);
  }
#pragma unroll
  for (int off = 32; off; off >>= 1) {
    mn = fminf(mn, __shfl_xor(mn, off, 64));
    mx = fmaxf(mx, __shfl_xor(mx, off, 64));
  }
  int wv = t >> 6;
  if ((t & 63) == 0) { red[wv] = mn; red[4 + wv] = mx; }
  __syncthreads();
  mn = fminf(fminf(red[0], red[1]), fminf(red[2], red[3]));
  mx = fmaxf(fmaxf(red[4], red[5]), fmaxf(red[6], red[7]));
  float inv = 1.f / (mx - mn + 1e-8f);
#pragma unroll
  for (int p2 = 0; p2 < 4; ++p2)
    out[(size_t)b * 1024 + t * 4 + p2] = (vals[p2] - mn) * inv;
}

// ---------------- launch ----------------
extern "C" void kernel_launch(void* const* d_in, const int* in_sizes, int n_in,
                              void* d_out, int out_size, void* d_ws, size_t ws_size,
                              hipStream_t stream) {
  const float* x     = (const float*)d_in[0];
  const float* W_emb = (const float*)d_in[1];
  const float* b_emb = (const float*)d_in[2];
  const float* Wq    = (const float*)d_in[3];
  const float* bq    = (const float*)d_in[4];
  const float* Wk    = (const float*)d_in[5];
  const float* bk    = (const float*)d_in[6];
  const float* Wv    = (const float*)d_in[7];
  const float* bv    = (const float*)d_in[8];
  const float* Wo    = (const float*)d_in[9];
  const float* bo    = (const float*)d_in[10];
  const float* W_un  = (const float*)d_in[11];
  const float* b_un  = (const float*)d_in[12];
  const float* W1    = (const float*)d_in[13];
  const float* b1    = (const float*)d_in[14];
  const float* W2    = (const float*)d_in[15];
  const float* b2    = (const float*)d_in[16];
  const float* W3    = (const float*)d_in[17];
  const float* b3    = (const float*)d_in[18];

  char* ws = (char*)d_ws;
  // layout:
  // [0, 16M):      hbf (h, reused as attn output o)
  // [16M, 32M):    q  -> after attn: xa (64K) | xabf (32K) | y3 (32K)
  // [32M, 48M):    k  -> after attn: w1T (2M) | w2T (2M) | w3T (256K) | y1bf (128K) | y2bf (32K)
  // [48M, 64M):    vT
  // [64M, ...):    wT qkv (1.5M) | woT (512K)
  unsigned short* hbf = (unsigned short*)(ws + 0);
  unsigned short* q   = (unsigned short*)(ws + 16777216);
  unsigned short* k   = (unsigned short*)(ws + 33554432);
  unsigned short* vT  = (unsigned short*)(ws + 50331648);
  unsigned short* wT  = (unsigned short*)(ws + 67108864);
  unsigned short* woT = (unsigned short*)(ws + 68681728);

  float*          xa   = (float*)(ws + 16777216);
  unsigned short* xabf = (unsigned short*)(ws + 16777216 + 65536);
  float*          y3   = (float*)(ws + 16777216 + 98304);
  unsigned short* w1T  = (unsigned short*)(ws + 33554432);
  unsigned short* w2T  = (unsigned short*)(ws + 35651584);
  unsigned short* w3T  = (unsigned short*)(ws + 37748736);
  unsigned short* y1bf = (unsigned short*)(ws + 38010880);
  unsigned short* y2bf = (unsigned short*)(ws + 38141952);

  float* out_y  = (float*)d_out;            // [32,1,16,64]
  float* out_xa = ((float*)d_out) + 32768;  // [32,512,1]

  // QKV/Wo weight transposes (bf16)
  k_transpose<<<dim3(16, 16), dim3(32, 8), 0, stream>>>(Wq, wT,                 512, 512);
  k_transpose<<<dim3(16, 16), dim3(32, 8), 0, stream>>>(Wk, wT + 512 * 512,     512, 512);
  k_transpose<<<dim3(16, 16), dim3(32, 8), 0, stream>>>(Wv, wT + 1024 * 512,    512, 512);
  k_transpose<<<dim3(16, 16), dim3(32, 8), 0, stream>>>(Wo, woT,                512, 512);

  k_embed<<<dim3(M_), dim3(256), 0, stream>>>(x, W_emb, b_emb, hbf);

  // fused QKV GEMM: [16384,512] @ [512,1536]
  k_mm128<0><<<dim3(1536), dim3(256), 0, stream>>>(
      hbf, wT, bq, bk, bv, nullptr, q, k, vT, nullptr, 12);

  k_attn<<<dim3(2, 256), dim3(256), 0, stream>>>(q, k, vT, hbf /* o reuses h */);

  // ff weight transposes (into dead k-region)
  k_transpose<<<dim3(64, 16), dim3(32, 8), 0, stream>>>(W1, w1T, 512, 2048);
  k_transpose<<<dim3(16, 64), dim3(32, 8), 0, stream>>>(W2, w2T, 2048, 512);
  k_transpose<<<dim3(8, 16),  dim3(32, 8), 0, stream>>>(W3, w3T, 512, 256);

  k_zero<<<dim3(64), dim3(256), 0, stream>>>(xa);

  // o @ Wo + bo, fused unembed -> xa
  k_mm128<1><<<dim3(512), dim3(256), 0, stream>>>(
      hbf, woT, bo, nullptr, nullptr, W_un, nullptr, nullptr, nullptr, xa, 4);

  k_xa_fin<<<dim3(64), dim3(256), 0, stream>>>(xa, b_un, out_xa, xabf);

  // ff chain (bf16 MFMA)
  k_ffmm<<<dim3(32), dim3(256), 0, stream>>>(xabf, w1T, b1, 512, 2048, 1, y1bf, nullptr);
  k_ffmm<<<dim3(8),  dim3(256), 0, stream>>>(y1bf, w2T, b2, 2048, 512, 1, y2bf, nullptr);
  k_ffmm<<<dim3(4),  dim3(256), 0, stream>>>(y2bf, w3T, b3, 512, 256, 0, nullptr, y3);

  k_up<<<dim3(B_), dim3(256), 0, stream>>>(y3, out_y);
}

// Round 3
// 318.095 us; speedup vs baseline: 1.9480x; 1.0004x over previous
//
#include <hip/hip_runtime.h>

#define B_  32
#define N_  512
#define D_  512
#define H_  8
#define DH_ 64
#define M_  (B_*N_)   // 16384

typedef __attribute__((ext_vector_type(4))) float          f32x4;
typedef __attribute__((ext_vector_type(8))) unsigned short us8;
typedef __attribute__((ext_vector_type(8))) __bf16         bf16x8;

__device__ __forceinline__ f32x4 mfma_bf16(us8 a, us8 b, f32x4 c) {
  return __builtin_amdgcn_mfma_f32_16x16x32_bf16(
      __builtin_bit_cast(bf16x8, a), __builtin_bit_cast(bf16x8, b), c, 0, 0, 0);
}

__device__ __forceinline__ unsigned short f2bf(float f) {  // RNE f32->bf16
  unsigned int u = __builtin_bit_cast(unsigned int, f);
  u = (u + 0x7FFFu + ((u >> 16) & 1u)) >> 16;
  return (unsigned short)u;
}

__device__ __forceinline__ us8 ldg8(const unsigned short* p) {
  return *reinterpret_cast<const us8*>(p);
}

typedef const unsigned int __attribute__((address_space(1)))* gas_ptr;
typedef unsigned int __attribute__((address_space(3)))* las_ptr;

__device__ __forceinline__ void gload16(const unsigned short* src, unsigned short* ldsdst) {
  __builtin_amdgcn_global_load_lds((gas_ptr)(const void*)src, (las_ptr)(void*)ldsdst, 16, 0, 0);
}

// ---------------- generic transpose fp32 [R][C] -> bf16 [C][R] ----------------
__global__ __launch_bounds__(256) void k_transpose(
    const float* __restrict__ src, unsigned short* __restrict__ dst, int R, int C) {
  __shared__ float t[32][33];
  int c0 = blockIdx.x * 32, r0 = blockIdx.y * 32;
  int tx = threadIdx.x, ty = threadIdx.y;
  for (int yy = ty; yy < 32; yy += 8)
    t[yy][tx] = src[(size_t)(r0 + yy) * C + c0 + tx];
  __syncthreads();
  for (int yy = ty; yy < 32; yy += 8)
    dst[(size_t)(c0 + yy) * R + r0 + tx] = f2bf(t[tx][yy]);
}

// ---------------- embed: h[m][d] = x[m]*W_emb[n][d] + b_emb[n][d] ----------------
__global__ __launch_bounds__(256) void k_embed(
    const float* __restrict__ x, const float* __restrict__ W_emb,
    const float* __restrict__ b_emb, unsigned short* __restrict__ hbf) {
  int m = blockIdx.x;
  int n = m & (N_ - 1);
  float xv = x[m];
  const float* wr = W_emb + n * D_;
  const float* br = b_emb + n * D_;
  for (int d = threadIdx.x; d < D_; d += 256)
    hbf[(size_t)m * D_ + d] = f2bf(xv * wr[d] + br[d]);
}

// ---------------- 128x128x64 LDS-staged MFMA GEMM (m97 structure) ----------------
// EPI=0: fused QKV epilogue (j in [0,1536): q / k / vT writes)
// EPI=1: Wo epilogue + fused unembed partial-dot -> atomicAdd(xa)
template<int EPI>
__global__ __launch_bounds__(256, 2) void k_mm128(
    const unsigned short* __restrict__ A,   // [16384][512] bf16
    const unsigned short* __restrict__ Bt,  // [N][512] bf16 (row j = output col j)
    const float* __restrict__ bias0, const float* __restrict__ bias1,
    const float* __restrict__ bias2,
    const float* __restrict__ Wun,          // EPI=1: [512][512] fp32
    unsigned short* __restrict__ o0, unsigned short* __restrict__ o1,
    unsigned short* __restrict__ o2,
    float* __restrict__ xa,                 // EPI=1: [16384] fp32 (pre-zeroed)
    int ntiles) {
  __shared__ __align__(16) unsigned short lds[2][2 * 128 * 64];
  const int K = 512;
  int nwg = gridDim.x;
  int cpx = nwg >> 3;                                   // nwg % 8 == 0
  int wgid = ((int)blockIdx.x & 7) * cpx + ((int)blockIdx.x >> 3);
  int mt = wgid / ntiles, nt = wgid - mt * ntiles;
  int m0 = mt * 128, n0 = nt * 128;
  int tid = threadIdx.x, wave = tid >> 6, lane = tid & 63;
  int lrow = lane & 15, g = lane >> 4;
  int wr = wave >> 1, wc = wave & 1;

  f32x4 acc[4][4];
#pragma unroll
  for (int i = 0; i < 4; ++i)
#pragma unroll
    for (int j = 0; j < 4; ++j) acc[i][j] = (f32x4){0.f, 0.f, 0.f, 0.f};

  int rseg_base = wave * 8 + (lane >> 3);   // +16 rows per i
  int coff = (lane & 7) * 8;

  // prologue stage buf0, k0=0
#pragma unroll
  for (int i = 0; i < 4; ++i) {
    int rs = i * 32 + rseg_base;            // (i*4+wave)*8 + lane>>3
    gload16(A  + (size_t)(m0 + rs) * K + coff, &lds[0][(i * 4 + wave) * 512]);
    gload16(Bt + (size_t)(n0 + rs) * K + coff, &lds[0][128 * 64 + (i * 4 + wave) * 512]);
  }
  __syncthreads();

  for (int ks = 0; ks < 8; ++ks) {
    if (ks < 7) {
      int k0 = (ks + 1) * 64;
      int buf = (ks + 1) & 1;
#pragma unroll
      for (int i = 0; i < 4; ++i) {
        int rs = i * 32 + rseg_base;
        gload16(A  + (size_t)(m0 + rs) * K + k0 + coff, &lds[buf][(i * 4 + wave) * 512]);
        gload16(Bt + (size_t)(n0 + rs) * K + k0 + coff, &lds[buf][128 * 64 + (i * 4 + wave) * 512]);
      }
    }
    const unsigned short* la = &lds[ks & 1][0];
    const unsigned short* lb = la + 128 * 64;
#pragma unroll
    for (int kk = 0; kk < 2; ++kk) {
      us8 aF[4], bF[4];
#pragma unroll
      for (int mi = 0; mi < 4; ++mi)
        aF[mi] = *reinterpret_cast<const us8*>(la + (wr * 64 + mi * 16 + lrow) * 64 + kk * 32 + g * 8);
#pragma unroll
      for (int ni = 0; ni < 4; ++ni)
        bF[ni] = *reinterpret_cast<const us8*>(lb + (wc * 64 + ni * 16 + lrow) * 64 + kk * 32 + g * 8);
#pragma unroll
      for (int mi = 0; mi < 4; ++mi)
#pragma unroll
        for (int ni = 0; ni < 4; ++ni)
          acc[mi][ni] = mfma_bf16(aF[mi], bF[ni], acc[mi][ni]);
    }
    __syncthreads();
  }

  if (EPI == 0) {
    // fused QKV writes
#pragma unroll
    for (int ni = 0; ni < 4; ++ni) {
      int j = n0 + wc * 64 + ni * 16 + lrow;
      int which = j >> 9, jj = j & 511, head = jj >> 6, dh = jj & 63;
      float bj = (which == 0 ? bias0 : which == 1 ? bias1 : bias2)[jj];
      unsigned short* base = (which == 0) ? o0 : (which == 1) ? o1 : o2;
#pragma unroll
      for (int mi = 0; mi < 4; ++mi) {
#pragma unroll
        for (int r = 0; r < 4; ++r) {
          int m = m0 + wr * 64 + mi * 16 + g * 4 + r;
          int b = m >> 9, n = m & 511;
          unsigned short v = f2bf(acc[mi][ni][r] + bj);
          if (which < 2) base[((size_t)(b * 8 + head) * 512 + n) * 64 + dh] = v;
          else           base[((size_t)(b * 8 + head) * 64 + dh) * 512 + n] = v;
        }
      }
    }
  } else {
    // Wo + fused unembed: xa[m] += sum_j (acc + bo[j]) * Wun[n][j]
    float part[16];
#pragma unroll
    for (int i = 0; i < 16; ++i) part[i] = 0.f;
#pragma unroll
    for (int ni = 0; ni < 4; ++ni) {
      int j = n0 + wc * 64 + ni * 16 + lrow;
      float bj = bias0[j];
#pragma unroll
      for (int mi = 0; mi < 4; ++mi) {
#pragma unroll
        for (int r = 0; r < 4; ++r) {
          int m = m0 + wr * 64 + mi * 16 + g * 4 + r;
          int n = m & 511;
          part[mi * 4 + r] += (acc[mi][ni][r] + bj) * Wun[(size_t)n * 512 + j];
        }
      }
    }
#pragma unroll
    for (int off = 1; off < 16; off <<= 1)
#pragma unroll
      for (int t2 = 0; t2 < 16; ++t2)
        part[t2] += __shfl_xor(part[t2], off, 64);
    if (lrow == 0) {
#pragma unroll
      for (int mi = 0; mi < 4; ++mi)
#pragma unroll
        for (int r = 0; r < 4; ++r)
          atomicAdd(&xa[m0 + wr * 64 + mi * 16 + g * 4 + r], part[mi * 4 + r]);
    }
  }
}

// ---------------- attention (unchanged from round 1, passing) ----------------
__global__ __launch_bounds__(256, 2) void k_attn(
    const unsigned short* __restrict__ q, const unsigned short* __restrict__ kk,
    const unsigned short* __restrict__ vT, unsigned short* __restrict__ o) {
  __shared__ __align__(16) unsigned short plds[4][16 * 512];
  int nhalf = blockIdx.x, bh = blockIdx.y;
  int b = bh >> 3, h = bh & 7;
  const unsigned short* qh = q  + (size_t)bh * (N_ * DH_);
  const unsigned short* kh = kk + (size_t)bh * (N_ * DH_);
  const unsigned short* vh = vT + (size_t)bh * (DH_ * N_);
  int wave = threadIdx.x >> 6, lane = threadIdx.x & 63;
  int lrow = lane & 15, g = lane >> 4;
  char* plw = (char*)&plds[wave][0];
  const float cexp = 0.18033688011112042f;  // log2(e)/8

  for (int t = 0; t < 4; ++t) {
    int n0 = nhalf * 256 + wave * 64 + t * 16;
    const unsigned short* qrow = qh + (size_t)(n0 + lrow) * DH_;
    us8 bq0 = ldg8(qrow + g * 8);
    us8 bq1 = ldg8(qrow + 32 + g * 8);
    f32x4 s[32];
#pragma unroll
    for (int mc = 0; mc < 32; ++mc) {
      const unsigned short* krow = kh + (size_t)(mc * 16 + lrow) * DH_;
      f32x4 a = (f32x4){0.f, 0.f, 0.f, 0.f};
      a = mfma_bf16(ldg8(krow + g * 8), bq0, a);
      a = mfma_bf16(ldg8(krow + 32 + g * 8), bq1, a);
      s[mc] = a;
    }
    float mx = -3.0e38f;
#pragma unroll
    for (int mc = 0; mc < 32; ++mc)
      mx = fmaxf(fmaxf(fmaxf(mx, s[mc][0]), fmaxf(s[mc][1], s[mc][2])), s[mc][3]);
    mx = fmaxf(mx, __shfl_xor(mx, 16, 64));
    mx = fmaxf(mx, __shfl_xor(mx, 32, 64));
    float sum = 0.f;
#pragma unroll
    for (int mc = 0; mc < 32; ++mc) {
#pragma unroll
      for (int r = 0; r < 4; ++r) {
        float p = exp2f((s[mc][r] - mx) * cexp);
        s[mc][r] = p;
        sum += p;
      }
    }
    sum += __shfl_xor(sum, 16, 64);
    sum += __shfl_xor(sum, 32, 64);
    float inv = 1.f / sum;
#pragma unroll
    for (int mc = 0; mc < 32; ++mc) {
      unsigned int w0 = (unsigned)f2bf(s[mc][0]) | ((unsigned)f2bf(s[mc][1]) << 16);
      unsigned int w1 = (unsigned)f2bf(s[mc][2]) | ((unsigned)f2bf(s[mc][3]) << 16);
      unsigned off = (unsigned)((lrow * 1024 + (mc * 16 + g * 4) * 2) ^ ((lrow & 7) << 4));
      *reinterpret_cast<uint2*>(plw + off) = make_uint2(w0, w1);
    }
    f32x4 oacc[4];
#pragma unroll
    for (int i = 0; i < 4; ++i) oacc[i] = (f32x4){0.f, 0.f, 0.f, 0.f};
#pragma unroll 4
    for (int mb = 0; mb < 16; ++mb) {
      int m0 = mb * 32 + g * 8;
      unsigned off = (unsigned)((lrow * 1024 + m0 * 2) ^ ((lrow & 7) << 4));
      us8 bp = *reinterpret_cast<const us8*>(plw + off);
#pragma unroll
      for (int db = 0; db < 4; ++db) {
        us8 av = ldg8(vh + (size_t)(db * 16 + lrow) * N_ + m0);
        oacc[db] = mfma_bf16(av, bp, oacc[db]);
      }
    }
    int n = n0 + lrow;
#pragma unroll
    for (int db = 0; db < 4; ++db) {
#pragma unroll
      for (int r = 0; r < 4; ++r) {
        int dh = db * 16 + g * 4 + r;
        o[((size_t)(b * N_ + n)) * D_ + h * DH_ + dh] = f2bf(oacc[db][r] * inv);
      }
    }
  }
}

// ---------------- zero xa ----------------
__global__ __launch_bounds__(256) void k_zero(float* __restrict__ p) {
  p[blockIdx.x * 256 + threadIdx.x] = 0.f;
}

// ---------------- xa finish: +b_un, write out_xa fp32 + xabf ----------------
__global__ __launch_bounds__(256) void k_xa_fin(
    const float* __restrict__ xa, const float* __restrict__ bun,
    float* __restrict__ out_xa, unsigned short* __restrict__ xabf) {
  int m = blockIdx.x * 256 + threadIdx.x;
  float v = xa[m] + bun[m & (N_ - 1)];
  out_xa[m] = v;
  xabf[m] = f2bf(v);
}

// ---------------- small M=32 MFMA GEMM for ff layers ----------------
__global__ __launch_bounds__(256) void k_ffmm(
    const unsigned short* __restrict__ A,   // [32][K] bf16
    const unsigned short* __restrict__ Bt,  // [N][K] bf16
    const float* __restrict__ bias, int K, int N, int outbf,
    unsigned short* __restrict__ obf, float* __restrict__ of) {
  int wave = threadIdx.x >> 6, lane = threadIdx.x & 63;
  int lrow = lane & 15, g = lane >> 4;
  int j = blockIdx.x * 64 + wave * 16 + lrow;
  f32x4 acc0 = (f32x4){0.f, 0.f, 0.f, 0.f}, acc1 = acc0;
  const unsigned short* brow = Bt + (size_t)j * K;
  for (int k0 = g * 8; k0 < K; k0 += 32) {
    us8 bfr = ldg8(brow + k0);
    acc0 = mfma_bf16(ldg8(A + (size_t)lrow * K + k0), bfr, acc0);
    acc1 = mfma_bf16(ldg8(A + (size_t)(16 + lrow) * K + k0), bfr, acc1);
  }
  float bj = bias[j];
#pragma unroll
  for (int r = 0; r < 4; ++r) {
    int mA = g * 4 + r, mB = 16 + g * 4 + r;
    float vA = acc0[r] + bj, vB = acc1[r] + bj;
    if (outbf) {
      obf[(size_t)mA * N + j] = f2bf(vA);
      obf[(size_t)mB * N + j] = f2bf(vB);
    } else {
      of[(size_t)mA * N + j] = vA;
      of[(size_t)mB * N + j] = vB;
    }
  }
}

// ---------------- bilinear upsample 8x32 -> 16x64 + min-max norm ----------------
__global__ __launch_bounds__(256) void k_up(
    const float* __restrict__ y3g, float* __restrict__ out) {
  __shared__ float y3[256];
  __shared__ float red[8];
  int b = blockIdx.x, t = threadIdx.x;
  y3[t] = y3g[(size_t)b * 256 + t];
  __syncthreads();
  float vals[4];
  float mn = 3.0e38f, mx = -3.0e38f;
#pragma unroll
  for (int p2 = 0; p2 < 4; ++p2) {
    int p = t * 4 + p2;
    int i = p >> 6, jj = p & 63;
    float sy = fmaxf((float)i * 0.5f - 0.25f, 0.0f);
    int y0 = (int)sy; float fy = sy - (float)y0;
    int y1i = min(y0 + 1, 7);
    float sx = fmaxf((float)jj * 0.5f - 0.25f, 0.0f);
    int x0 = (int)sx; float fx = sx - (float)x0;
    int x1 = min(x0 + 1, 31);
    float v00 = y3[y0 * 32 + x0], v01 = y3[y0 * 32 + x1];
    float v10 = y3[y1i * 32 + x0], v11 = y3[y1i * 32 + x1];
    float v = (1.f - fy) * ((1.f - fx) * v00 + fx * v01)
            +        fy  * ((1.f - fx) * v10 + fx * v11);
    vals[p2] = v;
    mn = fminf(mn, v); mx = fmaxf(mx, v);
  }
#pragma unroll
  for (int off = 32; off; off >>= 1) {
    mn = fminf(mn, __shfl_xor(mn, off, 64));
    mx = fmaxf(mx, __shfl_xor(mx, off, 64));
  }
  int wv = t >> 6;
  if ((t & 63) == 0) { red[wv] = mn; red[4 + wv] = mx; }
  __syncthreads();
  mn = fminf(fminf(red[0], red[1]), fminf(red[2], red[3]));
  mx = fmaxf(fmaxf(red[4], red[5]), fmaxf(red[6], red[7]));
  float inv = 1.f / (mx - mn + 1e-8f);
#pragma unroll
  for (int p2 = 0; p2 < 4; ++p2)
    out[(size_t)b * 1024 + t * 4 + p2] = (vals[p2] - mn) * inv;
}

// ---------------- launch ----------------
extern "C" void kernel_launch(void* const* d_in, const int* in_sizes, int n_in,
                              void* d_out, int out_size, void* d_ws, size_t ws_size,
                              hipStream_t stream) {
  const float* x     = (const float*)d_in[0];
  const float* W_emb = (const float*)d_in[1];
  const float* b_emb = (const float*)d_in[2];
  const float* Wq    = (const float*)d_in[3];
  const float* bq    = (const float*)d_in[4];
  const float* Wk    = (const float*)d_in[5];
  const float* bk    = (const float*)d_in[6];
  const float* Wv    = (const float*)d_in[7];
  const float* bv    = (const float*)d_in[8];
  const float* Wo    = (const float*)d_in[9];
  const float* bo    = (const float*)d_in[10];
  const float* W_un  = (const float*)d_in[11];
  const float* b_un  = (const float*)d_in[12];
  const float* W1    = (const float*)d_in[13];
  const float* b1    = (const float*)d_in[14];
  const float* W2    = (const float*)d_in[15];
  const float* b2    = (const float*)d_in[16];
  const float* W3    = (const float*)d_in[17];
  const float* b3    = (const float*)d_in[18];

  char* ws = (char*)d_ws;
  // layout:
  // [0, 16M):      hbf (h, reused as attn output o)
  // [16M, 32M):    q  -> after attn: xa (64K) | xabf (32K) | y3 (32K)
  // [32M, 48M):    k  -> after attn: w1T (2M) | w2T (2M) | w3T (256K) | y1bf (128K) | y2bf (32K)
  // [48M, 64M):    vT
  // [64M, ...):    wT qkv (1.5M) | woT (512K)
  unsigned short* hbf = (unsigned short*)(ws + 0);
  unsigned short* q   = (unsigned short*)(ws + 16777216);
  unsigned short* k   = (unsigned short*)(ws + 33554432);
  unsigned short* vT  = (unsigned short*)(ws + 50331648);
  unsigned short* wT  = (unsigned short*)(ws + 67108864);
  unsigned short* woT = (unsigned short*)(ws + 68681728);

  float*          xa   = (float*)(ws + 16777216);
  unsigned short* xabf = (unsigned short*)(ws + 16777216 + 65536);
  float*          y3   = (float*)(ws + 16777216 + 98304);
  unsigned short* w1T  = (unsigned short*)(ws + 33554432);
  unsigned short* w2T  = (unsigned short*)(ws + 35651584);
  unsigned short* w3T  = (unsigned short*)(ws + 37748736);
  unsigned short* y1bf = (unsigned short*)(ws + 38010880);
  unsigned short* y2bf = (unsigned short*)(ws + 38141952);

  float* out_y  = (float*)d_out;            // [32,1,16,64]
  float* out_xa = ((float*)d_out) + 32768;  // [32,512,1]

  // QKV/Wo weight transposes (bf16)
  k_transpose<<<dim3(16, 16), dim3(32, 8), 0, stream>>>(Wq, wT,                 512, 512);
  k_transpose<<<dim3(16, 16), dim3(32, 8), 0, stream>>>(Wk, wT + 512 * 512,     512, 512);
  k_transpose<<<dim3(16, 16), dim3(32, 8), 0, stream>>>(Wv, wT + 1024 * 512,    512, 512);
  k_transpose<<<dim3(16, 16), dim3(32, 8), 0, stream>>>(Wo, woT,                512, 512);

  k_embed<<<dim3(M_), dim3(256), 0, stream>>>(x, W_emb, b_emb, hbf);

  // fused QKV GEMM: [16384,512] @ [512,1536]
  k_mm128<0><<<dim3(1536), dim3(256), 0, stream>>>(
      hbf, wT, bq, bk, bv, nullptr, q, k, vT, nullptr, 12);

  k_attn<<<dim3(2, 256), dim3(256), 0, stream>>>(q, k, vT, hbf /* o reuses h */);

  // ff weight transposes (into dead k-region)
  k_transpose<<<dim3(64, 16), dim3(32, 8), 0, stream>>>(W1, w1T, 512, 2048);
  k_transpose<<<dim3(16, 64), dim3(32, 8), 0, stream>>>(W2, w2T, 2048, 512);
  k_transpose<<<dim3(8, 16),  dim3(32, 8), 0, stream>>>(W3, w3T, 512, 256);

  k_zero<<<dim3(64), dim3(256), 0, stream>>>(xa);

  // o @ Wo + bo, fused unembed -> xa
  k_mm128<1><<<dim3(512), dim3(256), 0, stream>>>(
      hbf, woT, bo, nullptr, nullptr, W_un, nullptr, nullptr, nullptr, xa, 4);

  k_xa_fin<<<dim3(64), dim3(256), 0, stream>>>(xa, b_un, out_xa, xabf);

  // ff chain (bf16 MFMA)
  k_ffmm<<<dim3(32), dim3(256), 0, stream>>>(xabf, w1T, b1, 512, 2048, 1, y1bf, nullptr);
  k_ffmm<<<dim3(8),  dim3(256), 0, stream>>>(y1bf, w2T, b2, 2048, 512, 1, y2bf, nullptr);
  k_ffmm<<<dim3(4),  dim3(256), 0, stream>>>(y2bf, w3T, b3, 512, 256, 0, nullptr, y3);

  k_up<<<dim3(B_), dim3(256), 0, stream>>>(y3, out_y);
}

// Round 4
// 214.049 us; speedup vs baseline: 2.8949x; 1.4861x over previous
//
#include <hip/hip_runtime.h>

#define B_  32
#define N_  512
#define D_  512
#define H_  8
#define DH_ 64
#define M_  (B_*N_)   // 16384

typedef __attribute__((ext_vector_type(4))) float          f32x4;
typedef __attribute__((ext_vector_type(8))) unsigned short us8;
typedef __attribute__((ext_vector_type(8))) __bf16         bf16x8;

__device__ __forceinline__ f32x4 mfma_bf16(us8 a, us8 b, f32x4 c) {
  return __builtin_amdgcn_mfma_f32_16x16x32_bf16(
      __builtin_bit_cast(bf16x8, a), __builtin_bit_cast(bf16x8, b), c, 0, 0, 0);
}

__device__ __forceinline__ unsigned short f2bf(float f) {  // RNE f32->bf16
  unsigned int u = __builtin_bit_cast(unsigned int, f);
  u = (u + 0x7FFFu + ((u >> 16) & 1u)) >> 16;
  return (unsigned short)u;
}

__device__ __forceinline__ us8 ldg8(const unsigned short* p) {
  return *reinterpret_cast<const us8*>(p);
}

typedef const unsigned int __attribute__((address_space(1)))* gas_ptr;
typedef unsigned int __attribute__((address_space(3)))* las_ptr;

__device__ __forceinline__ void gload16(const unsigned short* src, unsigned short* ldsdst) {
  __builtin_amdgcn_global_load_lds((gas_ptr)(const void*)src, (las_ptr)(void*)ldsdst, 16, 0, 0);
}

// ---------------- generic transpose fp32 [R][C] -> bf16 [C][R] ----------------
__global__ __launch_bounds__(256) void k_transpose(
    const float* __restrict__ src, unsigned short* __restrict__ dst, int R, int C) {
  __shared__ float t[32][33];
  int c0 = blockIdx.x * 32, r0 = blockIdx.y * 32;
  int tx = threadIdx.x, ty = threadIdx.y;
  for (int yy = ty; yy < 32; yy += 8)
    t[yy][tx] = src[(size_t)(r0 + yy) * C + c0 + tx];
  __syncthreads();
  for (int yy = ty; yy < 32; yy += 8)
    dst[(size_t)(c0 + yy) * R + r0 + tx] = f2bf(t[tx][yy]);
}

// ---------------- embed ----------------
__global__ __launch_bounds__(256) void k_embed(
    const float* __restrict__ x, const float* __restrict__ W_emb,
    const float* __restrict__ b_emb, unsigned short* __restrict__ hbf) {
  int m = blockIdx.x;
  int n = m & (N_ - 1);
  float xv = x[m];
  const float* wr = W_emb + n * D_;
  const float* br = b_emb + n * D_;
  for (int d = threadIdx.x; d < D_; d += 256)
    hbf[(size_t)m * D_ + d] = f2bf(xv * wr[d] + br[d]);
}

// ---------------- 128x128x64 LDS-staged MFMA GEMM ----------------
template<int EPI>
__global__ __launch_bounds__(256, 2) void k_mm128(
    const unsigned short* __restrict__ A,
    const unsigned short* __restrict__ Bt,
    const float* __restrict__ bias0, const float* __restrict__ bias1,
    const float* __restrict__ bias2,
    const float* __restrict__ Wun,
    unsigned short* __restrict__ o0, unsigned short* __restrict__ o1,
    unsigned short* __restrict__ o2,
    float* __restrict__ xa,
    int ntiles) {
  __shared__ __align__(16) unsigned short lds[2][2 * 128 * 64];
  const int K = 512;
  int nwg = gridDim.x;
  int cpx = nwg >> 3;
  int wgid = ((int)blockIdx.x & 7) * cpx + ((int)blockIdx.x >> 3);
  int mt = wgid / ntiles, nt = wgid - mt * ntiles;
  int m0 = mt * 128, n0 = nt * 128;
  int tid = threadIdx.x, wave = tid >> 6, lane = tid & 63;
  int lrow = lane & 15, g = lane >> 4;
  int wr = wave >> 1, wc = wave & 1;

  f32x4 acc[4][4];
#pragma unroll
  for (int i = 0; i < 4; ++i)
#pragma unroll
    for (int j = 0; j < 4; ++j) acc[i][j] = (f32x4){0.f, 0.f, 0.f, 0.f};

  int rseg_base = wave * 8 + (lane >> 3);
  int coff = (lane & 7) * 8;

#pragma unroll
  for (int i = 0; i < 4; ++i) {
    int rs = i * 32 + rseg_base;
    gload16(A  + (size_t)(m0 + rs) * K + coff, &lds[0][(i * 4 + wave) * 512]);
    gload16(Bt + (size_t)(n0 + rs) * K + coff, &lds[0][128 * 64 + (i * 4 + wave) * 512]);
  }
  __syncthreads();

  for (int ks = 0; ks < 8; ++ks) {
    if (ks < 7) {
      int k0 = (ks + 1) * 64;
      int buf = (ks + 1) & 1;
#pragma unroll
      for (int i = 0; i < 4; ++i) {
        int rs = i * 32 + rseg_base;
        gload16(A  + (size_t)(m0 + rs) * K + k0 + coff, &lds[buf][(i * 4 + wave) * 512]);
        gload16(Bt + (size_t)(n0 + rs) * K + k0 + coff, &lds[buf][128 * 64 + (i * 4 + wave) * 512]);
      }
    }
    const unsigned short* la = &lds[ks & 1][0];
    const unsigned short* lb = la + 128 * 64;
#pragma unroll
    for (int kk = 0; kk < 2; ++kk) {
      us8 aF[4], bF[4];
#pragma unroll
      for (int mi = 0; mi < 4; ++mi)
        aF[mi] = *reinterpret_cast<const us8*>(la + (wr * 64 + mi * 16 + lrow) * 64 + kk * 32 + g * 8);
#pragma unroll
      for (int ni = 0; ni < 4; ++ni)
        bF[ni] = *reinterpret_cast<const us8*>(lb + (wc * 64 + ni * 16 + lrow) * 64 + kk * 32 + g * 8);
#pragma unroll
      for (int mi = 0; mi < 4; ++mi)
#pragma unroll
        for (int ni = 0; ni < 4; ++ni)
          acc[mi][ni] = mfma_bf16(aF[mi], bF[ni], acc[mi][ni]);
    }
    __syncthreads();
  }

  if (EPI == 0) {
#pragma unroll
    for (int ni = 0; ni < 4; ++ni) {
      int j = n0 + wc * 64 + ni * 16 + lrow;
      int which = j >> 9, jj = j & 511, head = jj >> 6, dh = jj & 63;
      float bj = (which == 0 ? bias0 : which == 1 ? bias1 : bias2)[jj];
      unsigned short* base = (which == 0) ? o0 : (which == 1) ? o1 : o2;
#pragma unroll
      for (int mi = 0; mi < 4; ++mi) {
#pragma unroll
        for (int r = 0; r < 4; ++r) {
          int m = m0 + wr * 64 + mi * 16 + g * 4 + r;
          int b = m >> 9, n = m & 511;
          unsigned short v = f2bf(acc[mi][ni][r] + bj);
          if (which < 2) base[((size_t)(b * 8 + head) * 512 + n) * 64 + dh] = v;
          else           base[((size_t)(b * 8 + head) * 64 + dh) * 512 + n] = v;
        }
      }
    }
  } else {
    float part[16];
#pragma unroll
    for (int i = 0; i < 16; ++i) part[i] = 0.f;
#pragma unroll
    for (int ni = 0; ni < 4; ++ni) {
      int j = n0 + wc * 64 + ni * 16 + lrow;
      float bj = bias0[j];
#pragma unroll
      for (int mi = 0; mi < 4; ++mi) {
#pragma unroll
        for (int r = 0; r < 4; ++r) {
          int m = m0 + wr * 64 + mi * 16 + g * 4 + r;
          int n = m & 511;
          part[mi * 4 + r] += (acc[mi][ni][r] + bj) * Wun[(size_t)n * 512 + j];
        }
      }
    }
#pragma unroll
    for (int off = 1; off < 16; off <<= 1)
#pragma unroll
      for (int t2 = 0; t2 < 16; ++t2)
        part[t2] += __shfl_xor(part[t2], off, 64);
    if (lrow == 0) {
#pragma unroll
      for (int mi = 0; mi < 4; ++mi)
#pragma unroll
        for (int r = 0; r < 4; ++r)
          atomicAdd(&xa[m0 + wr * 64 + mi * 16 + g * 4 + r], part[mi * 4 + r]);
    }
  }
}

// ---------------- flash attention: 1 block per (b,h), 8 waves, KV staged in LDS ----------------
// K LDS layout: slot (mc_l*2+kk) of 1KB: element K[mc_l*16+lr][kk*32+g*8+e] at byte slot*1024 + (g*16+lr)*16 + e*2
// V LDS layout: slot (db*2+ks):          vT[db*16+lr][mb8*64+ks*32+g*8+e]  at byte slot*1024 + (g*16+lr)*16 + e*2
// P LDS layout (per wave, 2KB): P^T[m_l=ks*32+8*gp+e][n] at byte ks*1024 + gp*256 + n*16 + e*2
__global__ __launch_bounds__(512, 2) void k_attn(
    const unsigned short* __restrict__ q, const unsigned short* __restrict__ kk,
    const unsigned short* __restrict__ vT, unsigned short* __restrict__ o) {
  __shared__ __align__(16) unsigned short kbuf[2][4096];   // 8KB x2
  __shared__ __align__(16) unsigned short vbuf[2][4096];   // 8KB x2
  __shared__ __align__(16) unsigned short pbuf[8][1024];   // 2KB per wave
  int bh = blockIdx.x;
  int b = bh >> 3, h = bh & 7;
  const unsigned short* qh = q  + (size_t)bh * (N_ * DH_);
  const unsigned short* kh = kk + (size_t)bh * (N_ * DH_);
  const unsigned short* vh = vT + (size_t)bh * (DH_ * N_);
  int w = threadIdx.x >> 6, lane = threadIdx.x & 63;
  int lr = lane & 15, g = lane >> 4;
  const float cexp = 0.18033688011112042f;  // log2(e)/8

  // Q B-frags for this wave's 4 tiles (q rows w*64 + tt*16 + lr)
  us8 bq[4][2];
#pragma unroll
  for (int tt = 0; tt < 4; ++tt) {
    const unsigned short* qrow = qh + (size_t)(w * 64 + tt * 16 + lr) * DH_;
    bq[tt][0] = ldg8(qrow + g * 8);
    bq[tt][1] = ldg8(qrow + 32 + g * 8);
  }

  f32x4 oacc[4][4];
#pragma unroll
  for (int tt = 0; tt < 4; ++tt)
#pragma unroll
    for (int db = 0; db < 4; ++db) oacc[tt][db] = (f32x4){0.f, 0.f, 0.f, 0.f};
  float mrun[4] = {-3.0e38f, -3.0e38f, -3.0e38f, -3.0e38f};
  float lrun[4] = {0.f, 0.f, 0.f, 0.f};

  // staging: wave w fills K slot w and V slot w of the target buffer
  int k_mcl = w >> 1, k_kk = w & 1;           // K slot decomposition
  const unsigned short* ksrc_base = kh + (size_t)(k_mcl * 16 + lr) * DH_ + k_kk * 32 + g * 8;
  const unsigned short* vsrc_base = vh + (size_t)(k_mcl * 16 + lr) * N_  + k_kk * 32 + g * 8;  // db=w>>1, ks=w&1

  // prologue: stage block 0 -> buf 0
  gload16(ksrc_base, &kbuf[0][w * 512]);
  gload16(vsrc_base, &vbuf[0][w * 512]);

  char* pw = (char*)&pbuf[w][0];

  for (int mb8 = 0; mb8 < 8; ++mb8) {
    int cur = mb8 & 1;
    if (mb8 < 7) {
      gload16(ksrc_base + (size_t)(mb8 + 1) * 64 * DH_, &kbuf[cur ^ 1][w * 512]);
      gload16(vsrc_base + (mb8 + 1) * 64,               &vbuf[cur ^ 1][w * 512]);
    }
    __syncthreads();   // staged loads for `cur` drained (vmcnt0 at barrier)

    const char* kb = (const char*)&kbuf[cur][0];
    const char* vb = (const char*)&vbuf[cur][0];

#pragma unroll
    for (int tt = 0; tt < 4; ++tt) {
      // QK^T for this m-block: S^T[m_l][n=lr], lane holds m_l = mc_l*16 + 4g + r
      f32x4 s[4];
#pragma unroll
      for (int mc_l = 0; mc_l < 4; ++mc_l) {
        f32x4 a = (f32x4){0.f, 0.f, 0.f, 0.f};
        a = mfma_bf16(*(const us8*)(kb + (mc_l * 2 + 0) * 1024 + lane * 16), bq[tt][0], a);
        a = mfma_bf16(*(const us8*)(kb + (mc_l * 2 + 1) * 1024 + lane * 16), bq[tt][1], a);
        s[mc_l] = a;
      }
      // online softmax (raw-score units, 1/8*log2e folded into exp arg)
      float pmax = -3.0e38f;
#pragma unroll
      for (int mc_l = 0; mc_l < 4; ++mc_l)
        pmax = fmaxf(fmaxf(fmaxf(pmax, s[mc_l][0]), fmaxf(s[mc_l][1], s[mc_l][2])), s[mc_l][3]);
      pmax = fmaxf(pmax, __shfl_xor(pmax, 16, 64));
      pmax = fmaxf(pmax, __shfl_xor(pmax, 32, 64));
      float mnew = fmaxf(mrun[tt], pmax);
      float rs = exp2f((mrun[tt] - mnew) * cexp);
      mrun[tt] = mnew;
      lrun[tt] *= rs;
#pragma unroll
      for (int db = 0; db < 4; ++db) oacc[tt][db] *= rs;
      float lsum = 0.f;
#pragma unroll
      for (int mc_l = 0; mc_l < 4; ++mc_l) {
#pragma unroll
        for (int r = 0; r < 4; ++r) {
          float p = exp2f((s[mc_l][r] - mnew) * cexp);
          s[mc_l][r] = p;
          lsum += p;
        }
      }
      lsum += __shfl_xor(lsum, 16, 64);
      lsum += __shfl_xor(lsum, 32, 64);
      lrun[tt] += lsum;
      // P -> wave-private LDS chunk in B-frag layout
#pragma unroll
      for (int mc_l = 0; mc_l < 4; ++mc_l) {
        uint2 u;
        u.x = (unsigned)f2bf(s[mc_l][0]) | ((unsigned)f2bf(s[mc_l][1]) << 16);
        u.y = (unsigned)f2bf(s[mc_l][2]) | ((unsigned)f2bf(s[mc_l][3]) << 16);
        unsigned off = (unsigned)((mc_l >> 1) * 1024 + (((mc_l & 1) << 1) | (g >> 1)) * 256
                                  + lr * 16 + (g & 1) * 8);
        *reinterpret_cast<uint2*>(pw + off) = u;
      }
      // PV: O^T[dh][n] += V^T chunk . P^T chunk
#pragma unroll
      for (int ks = 0; ks < 2; ++ks) {
        us8 bp = *(const us8*)(pw + ks * 1024 + lane * 16);
#pragma unroll
        for (int db = 0; db < 4; ++db) {
          us8 av = *(const us8*)(vb + (db * 2 + ks) * 1024 + lane * 16);
          oacc[tt][db] = mfma_bf16(av, bp, oacc[tt][db]);
        }
      }
    }
    __syncthreads();   // all waves done with buf `cur` before it is re-staged
  }

  // epilogue: normalize + transpose through wave-private LDS, 64B-line global stores
#pragma unroll
  for (int tt = 0; tt < 4; ++tt) {
    float inv = 1.f / lrun[tt];
#pragma unroll
    for (int db = 0; db < 4; ++db) {
      uint2 u;
      u.x = (unsigned)f2bf(oacc[tt][db][0] * inv) | ((unsigned)f2bf(oacc[tt][db][1] * inv) << 16);
      u.y = (unsigned)f2bf(oacc[tt][db][2] * inv) | ((unsigned)f2bf(oacc[tt][db][3] * inv) << 16);
      unsigned off = (unsigned)(lr * 128 + ((db * 32 + g * 8) ^ ((lr & 7) << 4)));
      *reinterpret_cast<uint2*>(pw + off) = u;
    }
    int n_l = lane >> 2;
#pragma unroll
    for (int hh = 0; hh < 2; ++hh) {
      int c16 = (lane & 3) + 4 * hh;
      us8 vv = *(const us8*)(pw + n_l * 128 + ((c16 ^ (n_l & 7)) << 4));
      *reinterpret_cast<us8*>(o + ((size_t)(b * 512 + w * 64 + tt * 16 + n_l)) * D_
                               + h * 64 + c16 * 8) = vv;
    }
  }
}

// ---------------- zero xa ----------------
__global__ __launch_bounds__(256) void k_zero(float* __restrict__ p) {
  p[blockIdx.x * 256 + threadIdx.x] = 0.f;
}

// ---------------- xa finish ----------------
__global__ __launch_bounds__(256) void k_xa_fin(
    const float* __restrict__ xa, const float* __restrict__ bun,
    float* __restrict__ out_xa, unsigned short* __restrict__ xabf) {
  int m = blockIdx.x * 256 + threadIdx.x;
  float v = xa[m] + bun[m & (N_ - 1)];
  out_xa[m] = v;
  xabf[m] = f2bf(v);
}

// ---------------- small M=32 MFMA GEMM for ff layers ----------------
__global__ __launch_bounds__(256) void k_ffmm(
    const unsigned short* __restrict__ A,
    const unsigned short* __restrict__ Bt,
    const float* __restrict__ bias, int K, int N, int outbf,
    unsigned short* __restrict__ obf, float* __restrict__ of) {
  int wave = threadIdx.x >> 6, lane = threadIdx.x & 63;
  int lrow = lane & 15, g = lane >> 4;
  int j = blockIdx.x * 64 + wave * 16 + lrow;
  f32x4 acc0 = (f32x4){0.f, 0.f, 0.f, 0.f}, acc1 = acc0;
  const unsigned short* brow = Bt + (size_t)j * K;
  for (int k0 = g * 8; k0 < K; k0 += 32) {
    us8 bfr = ldg8(brow + k0);
    acc0 = mfma_bf16(ldg8(A + (size_t)lrow * K + k0), bfr, acc0);
    acc1 = mfma_bf16(ldg8(A + (size_t)(16 + lrow) * K + k0), bfr, acc1);
  }
  float bj = bias[j];
#pragma unroll
  for (int r = 0; r < 4; ++r) {
    int mA = g * 4 + r, mB = 16 + g * 4 + r;
    float vA = acc0[r] + bj, vB = acc1[r] + bj;
    if (outbf) {
      obf[(size_t)mA * N + j] = f2bf(vA);
      obf[(size_t)mB * N + j] = f2bf(vB);
    } else {
      of[(size_t)mA * N + j] = vA;
      of[(size_t)mB * N + j] = vB;
    }
  }
}

// ---------------- bilinear upsample + min-max norm ----------------
__global__ __launch_bounds__(256) void k_up(
    const float* __restrict__ y3g, float* __restrict__ out) {
  __shared__ float y3[256];
  __shared__ float red[8];
  int b = blockIdx.x, t = threadIdx.x;
  y3[t] = y3g[(size_t)b * 256 + t];
  __syncthreads();
  float vals[4];
  float mn = 3.0e38f, mx = -3.0e38f;
#pragma unroll
  for (int p2 = 0; p2 < 4; ++p2) {
    int p = t * 4 + p2;
    int i = p >> 6, jj = p & 63;
    float sy = fmaxf((float)i * 0.5f - 0.25f, 0.0f);
    int y0 = (int)sy; float fy = sy - (float)y0;
    int y1i = min(y0 + 1, 7);
    float sx = fmaxf((float)jj * 0.5f - 0.25f, 0.0f);
    int x0 = (int)sx; float fx = sx - (float)x0;
    int x1 = min(x0 + 1, 31);
    float v00 = y3[y0 * 32 + x0], v01 = y3[y0 * 32 + x1];
    float v10 = y3[y1i * 32 + x0], v11 = y3[y1i * 32 + x1];
    float v = (1.f - fy) * ((1.f - fx) * v00 + fx * v01)
            +        fy  * ((1.f - fx) * v10 + fx * v11);
    vals[p2] = v;
    mn = fminf(mn, v); mx = fmaxf(mx, v);
  }
#pragma unroll
  for (int off = 32; off; off >>= 1) {
    mn = fminf(mn, __shfl_xor(mn, off, 64));
    mx = fmaxf(mx, __shfl_xor(mx, off, 64));
  }
  int wv = t >> 6;
  if ((t & 63) == 0) { red[wv] = mn; red[4 + wv] = mx; }
  __syncthreads();
  mn = fminf(fminf(red[0], red[1]), fminf(red[2], red[3]));
  mx = fmaxf(fmaxf(red[4], red[5]), fmaxf(red[6], red[7]));
  float inv = 1.f / (mx - mn + 1e-8f);
#pragma unroll
  for (int p2 = 0; p2 < 4; ++p2)
    out[(size_t)b * 1024 + t * 4 + p2] = (vals[p2] - mn) * inv;
}

// ---------------- launch ----------------
extern "C" void kernel_launch(void* const* d_in, const int* in_sizes, int n_in,
                              void* d_out, int out_size, void* d_ws, size_t ws_size,
                              hipStream_t stream) {
  const float* x     = (const float*)d_in[0];
  const float* W_emb = (const float*)d_in[1];
  const float* b_emb = (const float*)d_in[2];
  const float* Wq    = (const float*)d_in[3];
  const float* bq    = (const float*)d_in[4];
  const float* Wk    = (const float*)d_in[5];
  const float* bk    = (const float*)d_in[6];
  const float* Wv    = (const float*)d_in[7];
  const float* bv    = (const float*)d_in[8];
  const float* Wo    = (const float*)d_in[9];
  const float* bo    = (const float*)d_in[10];
  const float* W_un  = (const float*)d_in[11];
  const float* b_un  = (const float*)d_in[12];
  const float* W1    = (const float*)d_in[13];
  const float* b1    = (const float*)d_in[14];
  const float* W2    = (const float*)d_in[15];
  const float* b2    = (const float*)d_in[16];
  const float* W3    = (const float*)d_in[17];
  const float* b3    = (const float*)d_in[18];

  char* ws = (char*)d_ws;
  unsigned short* hbf = (unsigned short*)(ws + 0);
  unsigned short* q   = (unsigned short*)(ws + 16777216);
  unsigned short* k   = (unsigned short*)(ws + 33554432);
  unsigned short* vT  = (unsigned short*)(ws + 50331648);
  unsigned short* wT  = (unsigned short*)(ws + 67108864);
  unsigned short* woT = (unsigned short*)(ws + 68681728);

  float*          xa   = (float*)(ws + 16777216);
  unsigned short* xabf = (unsigned short*)(ws + 16777216 + 65536);
  float*          y3   = (float*)(ws + 16777216 + 98304);
  unsigned short* w1T  = (unsigned short*)(ws + 33554432);
  unsigned short* w2T  = (unsigned short*)(ws + 35651584);
  unsigned short* w3T  = (unsigned short*)(ws + 37748736);
  unsigned short* y1bf = (unsigned short*)(ws + 38010880);
  unsigned short* y2bf = (unsigned short*)(ws + 38141952);

  float* out_y  = (float*)d_out;            // [32,1,16,64]
  float* out_xa = ((float*)d_out) + 32768;  // [32,512,1]

  k_transpose<<<dim3(16, 16), dim3(32, 8), 0, stream>>>(Wq, wT,              512, 512);
  k_transpose<<<dim3(16, 16), dim3(32, 8), 0, stream>>>(Wk, wT + 512 * 512,  512, 512);
  k_transpose<<<dim3(16, 16), dim3(32, 8), 0, stream>>>(Wv, wT + 1024 * 512, 512, 512);
  k_transpose<<<dim3(16, 16), dim3(32, 8), 0, stream>>>(Wo, woT,             512, 512);

  k_embed<<<dim3(M_), dim3(256), 0, stream>>>(x, W_emb, b_emb, hbf);

  k_mm128<0><<<dim3(1536), dim3(256), 0, stream>>>(
      hbf, wT, bq, bk, bv, nullptr, q, k, vT, nullptr, 12);

  k_attn<<<dim3(256), dim3(512), 0, stream>>>(q, k, vT, hbf /* o reuses h */);

  k_transpose<<<dim3(64, 16), dim3(32, 8), 0, stream>>>(W1, w1T, 512, 2048);
  k_transpose<<<dim3(16, 64), dim3(32, 8), 0, stream>>>(W2, w2T, 2048, 512);
  k_transpose<<<dim3(8, 16),  dim3(32, 8), 0, stream>>>(W3, w3T, 512, 256);

  k_zero<<<dim3(64), dim3(256), 0, stream>>>(xa);

  k_mm128<1><<<dim3(512), dim3(256), 0, stream>>>(
      hbf, woT, bo, nullptr, nullptr, W_un, nullptr, nullptr, nullptr, xa, 4);

  k_xa_fin<<<dim3(64), dim3(256), 0, stream>>>(xa, b_un, out_xa, xabf);

  k_ffmm<<<dim3(32), dim3(256), 0, stream>>>(xabf, w1T, b1, 512, 2048, 1, y1bf, nullptr);
  k_ffmm<<<dim3(8),  dim3(256), 0, stream>>>(y1bf, w2T, b2, 2048, 512, 1, y2bf, nullptr);
  k_ffmm<<<dim3(4),  dim3(256), 0, stream>>>(y2bf, w3T, b3, 512, 256, 0, nullptr, y3);

  k_up<<<dim3(B_), dim3(256), 0, stream>>>(y3, out_y);
}

// Round 5
// 206.260 us; speedup vs baseline: 3.0042x; 1.0378x over previous
//
#include <hip/hip_runtime.h>

#define B_  32
#define N_  512
#define D_  512
#define H_  8
#define DH_ 64
#define M_  (B_*N_)   // 16384

typedef __attribute__((ext_vector_type(4))) float          f32x4;
typedef __attribute__((ext_vector_type(4))) unsigned short us4;
typedef __attribute__((ext_vector_type(8))) unsigned short us8;
typedef __attribute__((ext_vector_type(8))) __bf16         bf16x8;

__device__ __forceinline__ f32x4 mfma_bf16(us8 a, us8 b, f32x4 c) {
  return __builtin_amdgcn_mfma_f32_16x16x32_bf16(
      __builtin_bit_cast(bf16x8, a), __builtin_bit_cast(bf16x8, b), c, 0, 0, 0);
}

__device__ __forceinline__ unsigned short f2bf(float f) {  // RNE f32->bf16
  unsigned int u = __builtin_bit_cast(unsigned int, f);
  u = (u + 0x7FFFu + ((u >> 16) & 1u)) >> 16;
  return (unsigned short)u;
}

__device__ __forceinline__ us8 ldg8(const unsigned short* p) {
  return *reinterpret_cast<const us8*>(p);
}

typedef const unsigned int __attribute__((address_space(1)))* gas_ptr;
typedef unsigned int __attribute__((address_space(3)))* las_ptr;

__device__ __forceinline__ void gload16(const unsigned short* src, unsigned short* ldsdst) {
  __builtin_amdgcn_global_load_lds((gas_ptr)(const void*)src, (las_ptr)(void*)ldsdst, 16, 0, 0);
}

// ---------------- 4x same-shape [512,512] transpose fp32 -> bf16 (Wq,Wk,Wv,Wo) ----------------
__global__ __launch_bounds__(256) void k_transpose4(
    const float* __restrict__ Wq, const float* __restrict__ Wk,
    const float* __restrict__ Wv, const float* __restrict__ Wo,
    unsigned short* __restrict__ dst) {   // wT(3x) then woT, contiguous
  __shared__ float t[32][33];
  int z = blockIdx.z;
  const float* src = (z == 0) ? Wq : (z == 1) ? Wk : (z == 2) ? Wv : Wo;
  unsigned short* out = dst + (size_t)z * (512 * 512);
  int c0 = blockIdx.x * 32, r0 = blockIdx.y * 32;
  int tx = threadIdx.x, ty = threadIdx.y;
  for (int yy = ty; yy < 32; yy += 8)
    t[yy][tx] = src[(size_t)(r0 + yy) * 512 + c0 + tx];
  __syncthreads();
  for (int yy = ty; yy < 32; yy += 8)
    out[(size_t)(c0 + yy) * 512 + r0 + tx] = f2bf(t[tx][yy]);
}

// ---------------- generic transpose fp32 [R][C] -> bf16 [C][R] ----------------
__global__ __launch_bounds__(256) void k_transpose(
    const float* __restrict__ src, unsigned short* __restrict__ dst, int R, int C) {
  __shared__ float t[32][33];
  int c0 = blockIdx.x * 32, r0 = blockIdx.y * 32;
  int tx = threadIdx.x, ty = threadIdx.y;
  for (int yy = ty; yy < 32; yy += 8)
    t[yy][tx] = src[(size_t)(r0 + yy) * C + c0 + tx];
  __syncthreads();
  for (int yy = ty; yy < 32; yy += 8)
    dst[(size_t)(c0 + yy) * R + r0 + tx] = f2bf(t[tx][yy]);
}

// ---------------- embed (vectorized x4) ----------------
__global__ __launch_bounds__(256) void k_embed(
    const float* __restrict__ x, const float* __restrict__ W_emb,
    const float* __restrict__ b_emb, unsigned short* __restrict__ hbf) {
  // 2M vec4 elements total; grid-stride
  for (int idx = blockIdx.x * 256 + threadIdx.x; idx < M_ * 128; idx += 2048 * 256) {
    int m = idx >> 7, d4 = idx & 127;
    int n = m & (N_ - 1);
    float xv = x[m];
    f32x4 wv = *reinterpret_cast<const f32x4*>(W_emb + (size_t)n * D_ + d4 * 4);
    f32x4 bv = *reinterpret_cast<const f32x4*>(b_emb + (size_t)n * D_ + d4 * 4);
    us4 o;
#pragma unroll
    for (int e = 0; e < 4; ++e) o[e] = f2bf(xv * wv[e] + bv[e]);
    *reinterpret_cast<us4*>(hbf + (size_t)m * D_ + d4 * 4) = o;
  }
}

// ---------------- 128x128x64 LDS-staged MFMA GEMM, XOR-swizzled LDS ----------------
// LDS layout: element [r][c] of tile at byte r*128 + ((c*2) ^ ((r&7)<<4)).
// Staging keeps gload_lds dest LINEAR; the global source column chunk is
// pre-permuted per lane: coff = ((lane&7)^(lane>>3))*8  (rule #21 both-sides).
template<int EPI>
__global__ __launch_bounds__(256, 2) void k_mm128(
    const unsigned short* __restrict__ A,
    const unsigned short* __restrict__ Bt,
    const float* __restrict__ bias0, const float* __restrict__ bias1,
    const float* __restrict__ bias2,
    const float* __restrict__ Wun,
    unsigned short* __restrict__ o0, unsigned short* __restrict__ o1,
    unsigned short* __restrict__ o2,
    float* __restrict__ xa,
    int ntiles) {
  __shared__ __align__(16) unsigned short lds[2][2 * 128 * 64];
  const int K = 512;
  int nwg = gridDim.x;
  int cpx = nwg >> 3;
  int wgid = ((int)blockIdx.x & 7) * cpx + ((int)blockIdx.x >> 3);
  int mt = wgid / ntiles, nt = wgid - mt * ntiles;
  int m0 = mt * 128, n0 = nt * 128;
  int tid = threadIdx.x, wave = tid >> 6, lane = tid & 63;
  int lrow = lane & 15, g = lane >> 4;
  int wr = wave >> 1, wc = wave & 1;

  f32x4 acc[4][4];
#pragma unroll
  for (int i = 0; i < 4; ++i)
#pragma unroll
    for (int j = 0; j < 4; ++j) acc[i][j] = (f32x4){0.f, 0.f, 0.f, 0.f};

  int rseg_base = wave * 8 + (lane >> 3);
  int coff = (((lane & 7) ^ (lane >> 3)) << 3);   // swizzled source chunk

#pragma unroll
  for (int i = 0; i < 4; ++i) {
    int rs = i * 32 + rseg_base;
    gload16(A  + (size_t)(m0 + rs) * K + coff, &lds[0][(i * 4 + wave) * 512]);
    gload16(Bt + (size_t)(n0 + rs) * K + coff, &lds[0][128 * 64 + (i * 4 + wave) * 512]);
  }
  __syncthreads();

  for (int ks = 0; ks < 8; ++ks) {
    if (ks < 7) {
      int k0 = (ks + 1) * 64;
      int buf = (ks + 1) & 1;
#pragma unroll
      for (int i = 0; i < 4; ++i) {
        int rs = i * 32 + rseg_base;
        gload16(A  + (size_t)(m0 + rs) * K + k0 + coff, &lds[buf][(i * 4 + wave) * 512]);
        gload16(Bt + (size_t)(n0 + rs) * K + k0 + coff, &lds[buf][128 * 64 + (i * 4 + wave) * 512]);
      }
    }
    const char* la = (const char*)&lds[ks & 1][0];
    const char* lb = la + 128 * 64 * 2;
    int sw = (lrow & 7) << 4;
#pragma unroll
    for (int kk = 0; kk < 2; ++kk) {
      us8 aF[4], bF[4];
#pragma unroll
      for (int mi = 0; mi < 4; ++mi)
        aF[mi] = *reinterpret_cast<const us8*>(
            la + (wr * 64 + mi * 16 + lrow) * 128 + ((kk * 64 + g * 16) ^ sw));
#pragma unroll
      for (int ni = 0; ni < 4; ++ni)
        bF[ni] = *reinterpret_cast<const us8*>(
            lb + (wc * 64 + ni * 16 + lrow) * 128 + ((kk * 64 + g * 16) ^ sw));
#pragma unroll
      for (int mi = 0; mi < 4; ++mi)
#pragma unroll
        for (int ni = 0; ni < 4; ++ni)
          acc[mi][ni] = mfma_bf16(aF[mi], bF[ni], acc[mi][ni]);
    }
    __syncthreads();
  }

  if (EPI == 0) {
#pragma unroll
    for (int ni = 0; ni < 4; ++ni) {
      int j = n0 + wc * 64 + ni * 16 + lrow;
      int which = j >> 9, jj = j & 511, head = jj >> 6, dh = jj & 63;
      float bj = (which == 0 ? bias0 : which == 1 ? bias1 : bias2)[jj];
      unsigned short* base = (which == 0) ? o0 : (which == 1) ? o1 : o2;
#pragma unroll
      for (int mi = 0; mi < 4; ++mi) {
#pragma unroll
        for (int r = 0; r < 4; ++r) {
          int m = m0 + wr * 64 + mi * 16 + g * 4 + r;
          int b = m >> 9, n = m & 511;
          unsigned short v = f2bf(acc[mi][ni][r] + bj);
          if (which < 2) base[((size_t)(b * 8 + head) * 512 + n) * 64 + dh] = v;
          else           base[((size_t)(b * 8 + head) * 64 + dh) * 512 + n] = v;
        }
      }
    }
  } else {
    float part[16];
#pragma unroll
    for (int i = 0; i < 16; ++i) part[i] = 0.f;
#pragma unroll
    for (int ni = 0; ni < 4; ++ni) {
      int j = n0 + wc * 64 + ni * 16 + lrow;
      float bj = bias0[j];
#pragma unroll
      for (int mi = 0; mi < 4; ++mi) {
#pragma unroll
        for (int r = 0; r < 4; ++r) {
          int m = m0 + wr * 64 + mi * 16 + g * 4 + r;
          int n = m & 511;
          part[mi * 4 + r] += (acc[mi][ni][r] + bj) * Wun[(size_t)n * 512 + j];
        }
      }
    }
#pragma unroll
    for (int off = 1; off < 16; off <<= 1)
#pragma unroll
      for (int t2 = 0; t2 < 16; ++t2)
        part[t2] += __shfl_xor(part[t2], off, 64);
    if (lrow == 0) {
#pragma unroll
      for (int mi = 0; mi < 4; ++mi)
#pragma unroll
        for (int r = 0; r < 4; ++r)
          atomicAdd(&xa[m0 + wr * 64 + mi * 16 + g * 4 + r], part[mi * 4 + r]);
    }
  }
}

// ---------------- flash attention: 1 block per (b,h), 8 waves, KV staged in LDS ----------------
__global__ __launch_bounds__(512, 2) void k_attn(
    const unsigned short* __restrict__ q, const unsigned short* __restrict__ kk,
    const unsigned short* __restrict__ vT, unsigned short* __restrict__ o) {
  __shared__ __align__(16) unsigned short kbuf[2][4096];
  __shared__ __align__(16) unsigned short vbuf[2][4096];
  __shared__ __align__(16) unsigned short pbuf[8][1024];
  int bh = blockIdx.x;
  int b = bh >> 3, h = bh & 7;
  const unsigned short* qh = q  + (size_t)bh * (N_ * DH_);
  const unsigned short* kh = kk + (size_t)bh * (N_ * DH_);
  const unsigned short* vh = vT + (size_t)bh * (DH_ * N_);
  int w = threadIdx.x >> 6, lane = threadIdx.x & 63;
  int lr = lane & 15, g = lane >> 4;
  const float cexp = 0.18033688011112042f;  // log2(e)/8

  us8 bq[4][2];
#pragma unroll
  for (int tt = 0; tt < 4; ++tt) {
    const unsigned short* qrow = qh + (size_t)(w * 64 + tt * 16 + lr) * DH_;
    bq[tt][0] = ldg8(qrow + g * 8);
    bq[tt][1] = ldg8(qrow + 32 + g * 8);
  }

  f32x4 oacc[4][4];
#pragma unroll
  for (int tt = 0; tt < 4; ++tt)
#pragma unroll
    for (int db = 0; db < 4; ++db) oacc[tt][db] = (f32x4){0.f, 0.f, 0.f, 0.f};
  float mrun[4] = {-3.0e38f, -3.0e38f, -3.0e38f, -3.0e38f};
  float lrun[4] = {0.f, 0.f, 0.f, 0.f};

  int k_mcl = w >> 1, k_kk = w & 1;
  const unsigned short* ksrc_base = kh + (size_t)(k_mcl * 16 + lr) * DH_ + k_kk * 32 + g * 8;
  const unsigned short* vsrc_base = vh + (size_t)(k_mcl * 16 + lr) * N_  + k_kk * 32 + g * 8;

  gload16(ksrc_base, &kbuf[0][w * 512]);
  gload16(vsrc_base, &vbuf[0][w * 512]);

  char* pw = (char*)&pbuf[w][0];

  for (int mb8 = 0; mb8 < 8; ++mb8) {
    int cur = mb8 & 1;
    if (mb8 < 7) {
      gload16(ksrc_base + (size_t)(mb8 + 1) * 64 * DH_, &kbuf[cur ^ 1][w * 512]);
      gload16(vsrc_base + (mb8 + 1) * 64,               &vbuf[cur ^ 1][w * 512]);
    }
    __syncthreads();

    const char* kb = (const char*)&kbuf[cur][0];
    const char* vb = (const char*)&vbuf[cur][0];

#pragma unroll
    for (int tt = 0; tt < 4; ++tt) {
      f32x4 s[4];
#pragma unroll
      for (int mc_l = 0; mc_l < 4; ++mc_l) {
        f32x4 a = (f32x4){0.f, 0.f, 0.f, 0.f};
        a = mfma_bf16(*(const us8*)(kb + (mc_l * 2 + 0) * 1024 + lane * 16), bq[tt][0], a);
        a = mfma_bf16(*(const us8*)(kb + (mc_l * 2 + 1) * 1024 + lane * 16), bq[tt][1], a);
        s[mc_l] = a;
      }
      float pmax = -3.0e38f;
#pragma unroll
      for (int mc_l = 0; mc_l < 4; ++mc_l)
        pmax = fmaxf(fmaxf(fmaxf(pmax, s[mc_l][0]), fmaxf(s[mc_l][1], s[mc_l][2])), s[mc_l][3]);
      pmax = fmaxf(pmax, __shfl_xor(pmax, 16, 64));
      pmax = fmaxf(pmax, __shfl_xor(pmax, 32, 64));
      float mnew = fmaxf(mrun[tt], pmax);
      float rs = exp2f((mrun[tt] - mnew) * cexp);
      mrun[tt] = mnew;
      lrun[tt] *= rs;
#pragma unroll
      for (int db = 0; db < 4; ++db) oacc[tt][db] *= rs;
      float lsum = 0.f;
#pragma unroll
      for (int mc_l = 0; mc_l < 4; ++mc_l) {
#pragma unroll
        for (int r = 0; r < 4; ++r) {
          float p = exp2f((s[mc_l][r] - mnew) * cexp);
          s[mc_l][r] = p;
          lsum += p;
        }
      }
      lsum += __shfl_xor(lsum, 16, 64);
      lsum += __shfl_xor(lsum, 32, 64);
      lrun[tt] += lsum;
#pragma unroll
      for (int mc_l = 0; mc_l < 4; ++mc_l) {
        uint2 u;
        u.x = (unsigned)f2bf(s[mc_l][0]) | ((unsigned)f2bf(s[mc_l][1]) << 16);
        u.y = (unsigned)f2bf(s[mc_l][2]) | ((unsigned)f2bf(s[mc_l][3]) << 16);
        unsigned off = (unsigned)((mc_l >> 1) * 1024 + (((mc_l & 1) << 1) | (g >> 1)) * 256
                                  + lr * 16 + (g & 1) * 8);
        *reinterpret_cast<uint2*>(pw + off) = u;
      }
#pragma unroll
      for (int ks = 0; ks < 2; ++ks) {
        us8 bp = *(const us8*)(pw + ks * 1024 + lane * 16);
#pragma unroll
        for (int db = 0; db < 4; ++db) {
          us8 av = *(const us8*)(vb + (db * 2 + ks) * 1024 + lane * 16);
          oacc[tt][db] = mfma_bf16(av, bp, oacc[tt][db]);
        }
      }
    }
    __syncthreads();
  }

#pragma unroll
  for (int tt = 0; tt < 4; ++tt) {
    float inv = 1.f / lrun[tt];
#pragma unroll
    for (int db = 0; db < 4; ++db) {
      uint2 u;
      u.x = (unsigned)f2bf(oacc[tt][db][0] * inv) | ((unsigned)f2bf(oacc[tt][db][1] * inv) << 16);
      u.y = (unsigned)f2bf(oacc[tt][db][2] * inv) | ((unsigned)f2bf(oacc[tt][db][3] * inv) << 16);
      unsigned off = (unsigned)(lr * 128 + ((db * 32 + g * 8) ^ ((lr & 7) << 4)));
      *reinterpret_cast<uint2*>(pw + off) = u;
    }
    int n_l = lane >> 2;
#pragma unroll
    for (int hh = 0; hh < 2; ++hh) {
      int c16 = (lane & 3) + 4 * hh;
      us8 vv = *(const us8*)(pw + n_l * 128 + ((c16 ^ (n_l & 7)) << 4));
      *reinterpret_cast<us8*>(o + ((size_t)(b * 512 + w * 64 + tt * 16 + n_l)) * D_
                               + h * 64 + c16 * 8) = vv;
    }
  }
}

// ---------------- zero xa ----------------
__global__ __launch_bounds__(256) void k_zero(float* __restrict__ p) {
  p[blockIdx.x * 256 + threadIdx.x] = 0.f;
}

// ---------------- xa finish ----------------
__global__ __launch_bounds__(256) void k_xa_fin(
    const float* __restrict__ xa, const float* __restrict__ bun,
    float* __restrict__ out_xa, unsigned short* __restrict__ xabf) {
  int m = blockIdx.x * 256 + threadIdx.x;
  float v = xa[m] + bun[m & (N_ - 1)];
  out_xa[m] = v;
  xabf[m] = f2bf(v);
}

// ---------------- small M=32 MFMA GEMM for ff layers ----------------
__global__ __launch_bounds__(256) void k_ffmm(
    const unsigned short* __restrict__ A,
    const unsigned short* __restrict__ Bt,
    const float* __restrict__ bias, int K, int N, int outbf,
    unsigned short* __restrict__ obf, float* __restrict__ of) {
  int wave = threadIdx.x >> 6, lane = threadIdx.x & 63;
  int lrow = lane & 15, g = lane >> 4;
  int j = blockIdx.x * 64 + wave * 16 + lrow;
  f32x4 acc0 = (f32x4){0.f, 0.f, 0.f, 0.f}, acc1 = acc0;
  const unsigned short* brow = Bt + (size_t)j * K;
  for (int k0 = g * 8; k0 < K; k0 += 32) {
    us8 bfr = ldg8(brow + k0);
    acc0 = mfma_bf16(ldg8(A + (size_t)lrow * K + k0), bfr, acc0);
    acc1 = mfma_bf16(ldg8(A + (size_t)(16 + lrow) * K + k0), bfr, acc1);
  }
  float bj = bias[j];
#pragma unroll
  for (int r = 0; r < 4; ++r) {
    int mA = g * 4 + r, mB = 16 + g * 4 + r;
    float vA = acc0[r] + bj, vB = acc1[r] + bj;
    if (outbf) {
      obf[(size_t)mA * N + j] = f2bf(vA);
      obf[(size_t)mB * N + j] = f2bf(vB);
    } else {
      of[(size_t)mA * N + j] = vA;
      of[(size_t)mB * N + j] = vB;
    }
  }
}

// ---------------- bilinear upsample + min-max norm ----------------
__global__ __launch_bounds__(256) void k_up(
    const float* __restrict__ y3g, float* __restrict__ out) {
  __shared__ float y3[256];
  __shared__ float red[8];
  int b = blockIdx.x, t = threadIdx.x;
  y3[t] = y3g[(size_t)b * 256 + t];
  __syncthreads();
  float vals[4];
  float mn = 3.0e38f, mx = -3.0e38f;
#pragma unroll
  for (int p2 = 0; p2 < 4; ++p2) {
    int p = t * 4 + p2;
    int i = p >> 6, jj = p & 63;
    float sy = fmaxf((float)i * 0.5f - 0.25f, 0.0f);
    int y0 = (int)sy; float fy = sy - (float)y0;
    int y1i = min(y0 + 1, 7);
    float sx = fmaxf((float)jj * 0.5f - 0.25f, 0.0f);
    int x0 = (int)sx; float fx = sx - (float)x0;
    int x1 = min(x0 + 1, 31);
    float v00 = y3[y0 * 32 + x0], v01 = y3[y0 * 32 + x1];
    float v10 = y3[y1i * 32 + x0], v11 = y3[y1i * 32 + x1];
    float v = (1.f - fy) * ((1.f - fx) * v00 + fx * v01)
            +        fy  * ((1.f - fx) * v10 + fx * v11);
    vals[p2] = v;
    mn = fminf(mn, v); mx = fmaxf(mx, v);
  }
#pragma unroll
  for (int off = 32; off; off >>= 1) {
    mn = fminf(mn, __shfl_xor(mn, off, 64));
    mx = fmaxf(mx, __shfl_xor(mx, off, 64));
  }
  int wv = t >> 6;
  if ((t & 63) == 0) { red[wv] = mn; red[4 + wv] = mx; }
  __syncthreads();
  mn = fminf(fminf(red[0], red[1]), fminf(red[2], red[3]));
  mx = fmaxf(fmaxf(red[4], red[5]), fmaxf(red[6], red[7]));
  float inv = 1.f / (mx - mn + 1e-8f);
#pragma unroll
  for (int p2 = 0; p2 < 4; ++p2)
    out[(size_t)b * 1024 + t * 4 + p2] = (vals[p2] - mn) * inv;
}

// ---------------- launch ----------------
extern "C" void kernel_launch(void* const* d_in, const int* in_sizes, int n_in,
                              void* d_out, int out_size, void* d_ws, size_t ws_size,
                              hipStream_t stream) {
  const float* x     = (const float*)d_in[0];
  const float* W_emb = (const float*)d_in[1];
  const float* b_emb = (const float*)d_in[2];
  const float* Wq    = (const float*)d_in[3];
  const float* bq    = (const float*)d_in[4];
  const float* Wk    = (const float*)d_in[5];
  const float* bk    = (const float*)d_in[6];
  const float* Wv    = (const float*)d_in[7];
  const float* bv    = (const float*)d_in[8];
  const float* Wo    = (const float*)d_in[9];
  const float* bo    = (const float*)d_in[10];
  const float* W_un  = (const float*)d_in[11];
  const float* b_un  = (const float*)d_in[12];
  const float* W1    = (const float*)d_in[13];
  const float* b1    = (const float*)d_in[14];
  const float* W2    = (const float*)d_in[15];
  const float* b2    = (const float*)d_in[16];
  const float* W3    = (const float*)d_in[17];
  const float* b3    = (const float*)d_in[18];

  char* ws = (char*)d_ws;
  unsigned short* hbf = (unsigned short*)(ws + 0);
  unsigned short* q   = (unsigned short*)(ws + 16777216);
  unsigned short* k   = (unsigned short*)(ws + 33554432);
  unsigned short* vT  = (unsigned short*)(ws + 50331648);
  unsigned short* wT  = (unsigned short*)(ws + 67108864);   // Wq^T,Wk^T,Wv^T,Wo^T contiguous
  unsigned short* woT = (unsigned short*)(ws + 68681728);

  float*          xa   = (float*)(ws + 16777216);
  unsigned short* xabf = (unsigned short*)(ws + 16777216 + 65536);
  float*          y3   = (float*)(ws + 16777216 + 98304);
  unsigned short* w1T  = (unsigned short*)(ws + 33554432);
  unsigned short* w2T  = (unsigned short*)(ws + 35651584);
  unsigned short* w3T  = (unsigned short*)(ws + 37748736);
  unsigned short* y1bf = (unsigned short*)(ws + 38010880);
  unsigned short* y2bf = (unsigned short*)(ws + 38141952);

  float* out_y  = (float*)d_out;            // [32,1,16,64]
  float* out_xa = ((float*)d_out) + 32768;  // [32,512,1]

  k_transpose4<<<dim3(16, 16, 4), dim3(32, 8), 0, stream>>>(Wq, Wk, Wv, Wo, wT);

  k_embed<<<dim3(2048), dim3(256), 0, stream>>>(x, W_emb, b_emb, hbf);

  k_mm128<0><<<dim3(1536), dim3(256), 0, stream>>>(
      hbf, wT, bq, bk, bv, nullptr, q, k, vT, nullptr, 12);

  k_attn<<<dim3(256), dim3(512), 0, stream>>>(q, k, vT, hbf /* o reuses h */);

  k_transpose<<<dim3(64, 16), dim3(32, 8), 0, stream>>>(W1, w1T, 512, 2048);
  k_transpose<<<dim3(16, 64), dim3(32, 8), 0, stream>>>(W2, w2T, 2048, 512);
  k_transpose<<<dim3(8, 16),  dim3(32, 8), 0, stream>>>(W3, w3T, 512, 256);

  k_zero<<<dim3(64), dim3(256), 0, stream>>>(xa);

  k_mm128<1><<<dim3(512), dim3(256), 0, stream>>>(
      hbf, woT, bo, nullptr, nullptr, W_un, nullptr, nullptr, nullptr, xa, 4);

  k_xa_fin<<<dim3(64), dim3(256), 0, stream>>>(xa, b_un, out_xa, xabf);

  k_ffmm<<<dim3(32), dim3(256), 0, stream>>>(xabf, w1T, b1, 512, 2048, 1, y1bf, nullptr);
  k_ffmm<<<dim3(8),  dim3(256), 0, stream>>>(y1bf, w2T, b2, 2048, 512, 1, y2bf, nullptr);
  k_ffmm<<<dim3(4),  dim3(256), 0, stream>>>(y2bf, w3T, b3, 512, 256, 0, nullptr, y3);

  k_up<<<dim3(B_), dim3(256), 0, stream>>>(y3, out_y);
}

// Round 6
// 183.879 us; speedup vs baseline: 3.3699x; 1.1217x over previous
//
#include <hip/hip_runtime.h>

#define B_  32
#define N_  512
#define D_  512
#define H_  8
#define DH_ 64
#define M_  (B_*N_)   // 16384

typedef __attribute__((ext_vector_type(4))) float          f32x4;
typedef __attribute__((ext_vector_type(4))) unsigned short us4;
typedef __attribute__((ext_vector_type(8))) unsigned short us8;
typedef __attribute__((ext_vector_type(8))) __bf16         bf16x8;

__device__ __forceinline__ f32x4 mfma_bf16(us8 a, us8 b, f32x4 c) {
  return __builtin_amdgcn_mfma_f32_16x16x32_bf16(
      __builtin_bit_cast(bf16x8, a), __builtin_bit_cast(bf16x8, b), c, 0, 0, 0);
}

__device__ __forceinline__ unsigned short f2bf(float f) {  // hw RNE cvt
  return __builtin_bit_cast(unsigned short, (__bf16)f);
}

__device__ __forceinline__ float fexp2(float x) {  // raw v_exp_f32 (args bounded <=0, > -126)
  float r;
  asm("v_exp_f32 %0, %1" : "=v"(r) : "v"(x));
  return r;
}

__device__ __forceinline__ us8 ldg8(const unsigned short* p) {
  return *reinterpret_cast<const us8*>(p);
}

typedef const unsigned int __attribute__((address_space(1)))* gas_ptr;
typedef unsigned int __attribute__((address_space(3)))* las_ptr;

__device__ __forceinline__ void gload16(const unsigned short* src, unsigned short* ldsdst) {
  __builtin_amdgcn_global_load_lds((gas_ptr)(const void*)src, (las_ptr)(void*)ldsdst, 16, 0, 0);
}

// ---------------- 4x same-shape [512,512] transpose fp32 -> bf16 (Wq,Wk,Wv,Wo) ----------------
__global__ __launch_bounds__(256) void k_transpose4(
    const float* __restrict__ Wq, const float* __restrict__ Wk,
    const float* __restrict__ Wv, const float* __restrict__ Wo,
    unsigned short* __restrict__ dst) {
  __shared__ float t[32][33];
  int z = blockIdx.z;
  const float* src = (z == 0) ? Wq : (z == 1) ? Wk : (z == 2) ? Wv : Wo;
  unsigned short* out = dst + (size_t)z * (512 * 512);
  int c0 = blockIdx.x * 32, r0 = blockIdx.y * 32;
  int tx = threadIdx.x, ty = threadIdx.y;
  for (int yy = ty; yy < 32; yy += 8)
    t[yy][tx] = src[(size_t)(r0 + yy) * 512 + c0 + tx];
  __syncthreads();
  for (int yy = ty; yy < 32; yy += 8)
    out[(size_t)(c0 + yy) * 512 + r0 + tx] = f2bf(t[tx][yy]);
}

// ---------------- generic transpose fp32 [R][C] -> bf16 [C][R] ----------------
__global__ __launch_bounds__(256) void k_transpose(
    const float* __restrict__ src, unsigned short* __restrict__ dst, int R, int C) {
  __shared__ float t[32][33];
  int c0 = blockIdx.x * 32, r0 = blockIdx.y * 32;
  int tx = threadIdx.x, ty = threadIdx.y;
  for (int yy = ty; yy < 32; yy += 8)
    t[yy][tx] = src[(size_t)(r0 + yy) * C + c0 + tx];
  __syncthreads();
  for (int yy = ty; yy < 32; yy += 8)
    dst[(size_t)(c0 + yy) * R + r0 + tx] = f2bf(t[tx][yy]);
}

// ---------------- embed (vectorized x4) ----------------
__global__ __launch_bounds__(256) void k_embed(
    const float* __restrict__ x, const float* __restrict__ W_emb,
    const float* __restrict__ b_emb, unsigned short* __restrict__ hbf) {
  for (int idx = blockIdx.x * 256 + threadIdx.x; idx < M_ * 128; idx += 2048 * 256) {
    int m = idx >> 7, d4 = idx & 127;
    int n = m & (N_ - 1);
    float xv = x[m];
    f32x4 wv = *reinterpret_cast<const f32x4*>(W_emb + (size_t)n * D_ + d4 * 4);
    f32x4 bv = *reinterpret_cast<const f32x4*>(b_emb + (size_t)n * D_ + d4 * 4);
    us4 o;
#pragma unroll
    for (int e = 0; e < 4; ++e) o[e] = f2bf(xv * wv[e] + bv[e]);
    *reinterpret_cast<us4*>(hbf + (size_t)m * D_ + d4 * 4) = o;
  }
}

// ---------------- 128x128x64 LDS-staged MFMA GEMM, XOR-swizzled LDS ----------------
template<int EPI>
__global__ __launch_bounds__(256, 2) void k_mm128(
    const unsigned short* __restrict__ A,
    const unsigned short* __restrict__ Bt,
    const float* __restrict__ bias0, const float* __restrict__ bias1,
    const float* __restrict__ bias2,
    const float* __restrict__ Wun,
    unsigned short* __restrict__ o0, unsigned short* __restrict__ o1,
    unsigned short* __restrict__ o2,
    float* __restrict__ xa,
    int ntiles) {
  __shared__ __align__(16) unsigned short lds[2][2 * 128 * 64];
  const int K = 512;
  int nwg = gridDim.x;
  int cpx = nwg >> 3;
  int wgid = ((int)blockIdx.x & 7) * cpx + ((int)blockIdx.x >> 3);
  int mt = wgid / ntiles, nt = wgid - mt * ntiles;
  int m0 = mt * 128, n0 = nt * 128;
  int tid = threadIdx.x, wave = tid >> 6, lane = tid & 63;
  int lrow = lane & 15, g = lane >> 4;
  int wr = wave >> 1, wc = wave & 1;

  f32x4 acc[4][4];
#pragma unroll
  for (int i = 0; i < 4; ++i)
#pragma unroll
    for (int j = 0; j < 4; ++j) acc[i][j] = (f32x4){0.f, 0.f, 0.f, 0.f};

  int rseg_base = wave * 8 + (lane >> 3);
  int coff = (((lane & 7) ^ (lane >> 3)) << 3);   // swizzled source chunk

#pragma unroll
  for (int i = 0; i < 4; ++i) {
    int rs = i * 32 + rseg_base;
    gload16(A  + (size_t)(m0 + rs) * K + coff, &lds[0][(i * 4 + wave) * 512]);
    gload16(Bt + (size_t)(n0 + rs) * K + coff, &lds[0][128 * 64 + (i * 4 + wave) * 512]);
  }
  __syncthreads();

  for (int ks = 0; ks < 8; ++ks) {
    if (ks < 7) {
      int k0 = (ks + 1) * 64;
      int buf = (ks + 1) & 1;
#pragma unroll
      for (int i = 0; i < 4; ++i) {
        int rs = i * 32 + rseg_base;
        gload16(A  + (size_t)(m0 + rs) * K + k0 + coff, &lds[buf][(i * 4 + wave) * 512]);
        gload16(Bt + (size_t)(n0 + rs) * K + k0 + coff, &lds[buf][128 * 64 + (i * 4 + wave) * 512]);
      }
    }
    const char* la = (const char*)&lds[ks & 1][0];
    const char* lb = la + 128 * 64 * 2;
    int sw = (lrow & 7) << 4;
#pragma unroll
    for (int kk = 0; kk < 2; ++kk) {
      us8 aF[4], bF[4];
#pragma unroll
      for (int mi = 0; mi < 4; ++mi)
        aF[mi] = *reinterpret_cast<const us8*>(
            la + (wr * 64 + mi * 16 + lrow) * 128 + ((kk * 64 + g * 16) ^ sw));
#pragma unroll
      for (int ni = 0; ni < 4; ++ni)
        bF[ni] = *reinterpret_cast<const us8*>(
            lb + (wc * 64 + ni * 16 + lrow) * 128 + ((kk * 64 + g * 16) ^ sw));
#pragma unroll
      for (int mi = 0; mi < 4; ++mi)
#pragma unroll
        for (int ni = 0; ni < 4; ++ni)
          acc[mi][ni] = mfma_bf16(aF[mi], bF[ni], acc[mi][ni]);
    }
    __syncthreads();
  }

  if (EPI == 0) {
#pragma unroll
    for (int ni = 0; ni < 4; ++ni) {
      int j = n0 + wc * 64 + ni * 16 + lrow;
      int which = j >> 9, jj = j & 511, head = jj >> 6, dh = jj & 63;
      float bj = (which == 0 ? bias0 : which == 1 ? bias1 : bias2)[jj];
      unsigned short* base = (which == 0) ? o0 : (which == 1) ? o1 : o2;
#pragma unroll
      for (int mi = 0; mi < 4; ++mi) {
#pragma unroll
        for (int r = 0; r < 4; ++r) {
          int m = m0 + wr * 64 + mi * 16 + g * 4 + r;
          int b = m >> 9, n = m & 511;
          unsigned short v = f2bf(acc[mi][ni][r] + bj);
          if (which < 2) base[((size_t)(b * 8 + head) * 512 + n) * 64 + dh] = v;
          else           base[((size_t)(b * 8 + head) * 64 + dh) * 512 + n] = v;
        }
      }
    }
  } else {
    float part[16];
#pragma unroll
    for (int i = 0; i < 16; ++i) part[i] = 0.f;
#pragma unroll
    for (int ni = 0; ni < 4; ++ni) {
      int j = n0 + wc * 64 + ni * 16 + lrow;
      float bj = bias0[j];
#pragma unroll
      for (int mi = 0; mi < 4; ++mi) {
#pragma unroll
        for (int r = 0; r < 4; ++r) {
          int m = m0 + wr * 64 + mi * 16 + g * 4 + r;
          int n = m & 511;
          part[mi * 4 + r] += (acc[mi][ni][r] + bj) * Wun[(size_t)n * 512 + j];
        }
      }
    }
#pragma unroll
    for (int off = 1; off < 16; off <<= 1)
#pragma unroll
      for (int t2 = 0; t2 < 16; ++t2)
        part[t2] += __shfl_xor(part[t2], off, 64);
    if (lrow == 0) {
#pragma unroll
      for (int mi = 0; mi < 4; ++mi)
#pragma unroll
        for (int r = 0; r < 4; ++r)
          atomicAdd(&xa[m0 + wr * 64 + mi * 16 + g * 4 + r], part[mi * 4 + r]);
    }
  }
}

// ---------------- flash attention: 2 blocks per (b,h), 8 waves x 2 q-tiles ----------------
// Defer-max online softmax (THR=8 exp2-units); raw v_exp_f32; hw bf16 cvt.
__global__ __launch_bounds__(512, 4) void k_attn(
    const unsigned short* __restrict__ q, const unsigned short* __restrict__ kk,
    const unsigned short* __restrict__ vT, unsigned short* __restrict__ o) {
  __shared__ __align__(16) unsigned short kbuf[2][4096];
  __shared__ __align__(16) unsigned short vbuf[2][4096];
  __shared__ __align__(16) unsigned short pbuf[8][1024];
  int bh = blockIdx.x >> 1, half = blockIdx.x & 1;
  int b = bh >> 3, h = bh & 7;
  const unsigned short* qh = q  + (size_t)bh * (N_ * DH_);
  const unsigned short* kh = kk + (size_t)bh * (N_ * DH_);
  const unsigned short* vh = vT + (size_t)bh * (DH_ * N_);
  int w = threadIdx.x >> 6, lane = threadIdx.x & 63;
  int lr = lane & 15, g = lane >> 4;
  const float cexp = 0.18033688011112042f;   // log2(e)/8
  const float THRraw = 44.35f;               // 8 / cexp

  us8 bq[2][2];
#pragma unroll
  for (int tt = 0; tt < 2; ++tt) {
    const unsigned short* qrow = qh + (size_t)(half * 256 + w * 32 + tt * 16 + lr) * DH_;
    bq[tt][0] = ldg8(qrow + g * 8);
    bq[tt][1] = ldg8(qrow + 32 + g * 8);
  }

  f32x4 oacc[2][4];
#pragma unroll
  for (int tt = 0; tt < 2; ++tt)
#pragma unroll
    for (int db = 0; db < 4; ++db) oacc[tt][db] = (f32x4){0.f, 0.f, 0.f, 0.f};
  float mrun[2] = {-3.0e38f, -3.0e38f};
  float lrun[2] = {0.f, 0.f};

  int k_mcl = w >> 1, k_kk = w & 1;
  const unsigned short* ksrc_base = kh + (size_t)(k_mcl * 16 + lr) * DH_ + k_kk * 32 + g * 8;
  const unsigned short* vsrc_base = vh + (size_t)(k_mcl * 16 + lr) * N_  + k_kk * 32 + g * 8;

  gload16(ksrc_base, &kbuf[0][w * 512]);
  gload16(vsrc_base, &vbuf[0][w * 512]);

  char* pw = (char*)&pbuf[w][0];

  for (int mb8 = 0; mb8 < 8; ++mb8) {
    int cur = mb8 & 1;
    if (mb8 < 7) {
      gload16(ksrc_base + (size_t)(mb8 + 1) * 64 * DH_, &kbuf[cur ^ 1][w * 512]);
      gload16(vsrc_base + (mb8 + 1) * 64,               &vbuf[cur ^ 1][w * 512]);
    }
    __syncthreads();

    const char* kb = (const char*)&kbuf[cur][0];
    const char* vb = (const char*)&vbuf[cur][0];

#pragma unroll
    for (int tt = 0; tt < 2; ++tt) {
      f32x4 s[4];
#pragma unroll
      for (int mc_l = 0; mc_l < 4; ++mc_l) {
        f32x4 a = (f32x4){0.f, 0.f, 0.f, 0.f};
        a = mfma_bf16(*(const us8*)(kb + (mc_l * 2 + 0) * 1024 + lane * 16), bq[tt][0], a);
        a = mfma_bf16(*(const us8*)(kb + (mc_l * 2 + 1) * 1024 + lane * 16), bq[tt][1], a);
        s[mc_l] = a;
      }
      float pmax = fmaxf(fmaxf(s[0][0], s[0][1]), fmaxf(s[0][2], s[0][3]));
#pragma unroll
      for (int mc_l = 1; mc_l < 4; ++mc_l)
        pmax = fmaxf(pmax, fmaxf(fmaxf(s[mc_l][0], s[mc_l][1]), fmaxf(s[mc_l][2], s[mc_l][3])));
      pmax = fmaxf(pmax, __shfl_xor(pmax, 16, 64));
      pmax = fmaxf(pmax, __shfl_xor(pmax, 32, 64));
      if (__any(pmax > mrun[tt] + THRraw)) {   // rare after first block (defer-max)
        float mnew = fmaxf(mrun[tt], pmax);
        float rs = fexp2((mrun[tt] - mnew) * cexp);
        mrun[tt] = mnew;
        lrun[tt] *= rs;
#pragma unroll
        for (int db = 0; db < 4; ++db) oacc[tt][db] *= rs;
      }
      float mcur = mrun[tt];
      float lsum = 0.f;
#pragma unroll
      for (int mc_l = 0; mc_l < 4; ++mc_l) {
#pragma unroll
        for (int r = 0; r < 4; ++r) {
          float p = fexp2((s[mc_l][r] - mcur) * cexp);
          s[mc_l][r] = p;
          lsum += p;
        }
      }
      lsum += __shfl_xor(lsum, 16, 64);
      lsum += __shfl_xor(lsum, 32, 64);
      lrun[tt] += lsum;
#pragma unroll
      for (int mc_l = 0; mc_l < 4; ++mc_l) {
        uint2 u;
        u.x = (unsigned)f2bf(s[mc_l][0]) | ((unsigned)f2bf(s[mc_l][1]) << 16);
        u.y = (unsigned)f2bf(s[mc_l][2]) | ((unsigned)f2bf(s[mc_l][3]) << 16);
        unsigned off = (unsigned)((mc_l >> 1) * 1024 + (((mc_l & 1) << 1) | (g >> 1)) * 256
                                  + lr * 16 + (g & 1) * 8);
        *reinterpret_cast<uint2*>(pw + off) = u;
      }
#pragma unroll
      for (int ks = 0; ks < 2; ++ks) {
        us8 bp = *(const us8*)(pw + ks * 1024 + lane * 16);
#pragma unroll
        for (int db = 0; db < 4; ++db) {
          us8 av = *(const us8*)(vb + (db * 2 + ks) * 1024 + lane * 16);
          oacc[tt][db] = mfma_bf16(av, bp, oacc[tt][db]);
        }
      }
    }
    __syncthreads();
  }

#pragma unroll
  for (int tt = 0; tt < 2; ++tt) {
    float inv = 1.f / lrun[tt];
#pragma unroll
    for (int db = 0; db < 4; ++db) {
      uint2 u;
      u.x = (unsigned)f2bf(oacc[tt][db][0] * inv) | ((unsigned)f2bf(oacc[tt][db][1] * inv) << 16);
      u.y = (unsigned)f2bf(oacc[tt][db][2] * inv) | ((unsigned)f2bf(oacc[tt][db][3] * inv) << 16);
      unsigned off = (unsigned)(lr * 128 + ((db * 32 + g * 8) ^ ((lr & 7) << 4)));
      *reinterpret_cast<uint2*>(pw + off) = u;
    }
    int n_l = lane >> 2;
#pragma unroll
    for (int hh = 0; hh < 2; ++hh) {
      int c16 = (lane & 3) + 4 * hh;
      us8 vv = *(const us8*)(pw + n_l * 128 + ((c16 ^ (n_l & 7)) << 4));
      *reinterpret_cast<us8*>(o + ((size_t)(b * 512 + half * 256 + w * 32 + tt * 16 + n_l)) * D_
                               + h * 64 + c16 * 8) = vv;
    }
  }
}

// ---------------- zero xa ----------------
__global__ __launch_bounds__(256) void k_zero(float* __restrict__ p) {
  p[blockIdx.x * 256 + threadIdx.x] = 0.f;
}

// ---------------- xa finish ----------------
__global__ __launch_bounds__(256) void k_xa_fin(
    const float* __restrict__ xa, const float* __restrict__ bun,
    float* __restrict__ out_xa, unsigned short* __restrict__ xabf) {
  int m = blockIdx.x * 256 + threadIdx.x;
  float v = xa[m] + bun[m & (N_ - 1)];
  out_xa[m] = v;
  xabf[m] = f2bf(v);
}

// ---------------- small M=32 MFMA GEMM for ff layers ----------------
__global__ __launch_bounds__(256) void k_ffmm(
    const unsigned short* __restrict__ A,
    const unsigned short* __restrict__ Bt,
    const float* __restrict__ bias, int K, int N, int outbf,
    unsigned short* __restrict__ obf, float* __restrict__ of) {
  int wave = threadIdx.x >> 6, lane = threadIdx.x & 63;
  int lrow = lane & 15, g = lane >> 4;
  int j = blockIdx.x * 64 + wave * 16 + lrow;
  f32x4 acc0 = (f32x4){0.f, 0.f, 0.f, 0.f}, acc1 = acc0;
  const unsigned short* brow = Bt + (size_t)j * K;
  for (int k0 = g * 8; k0 < K; k0 += 32) {
    us8 bfr = ldg8(brow + k0);
    acc0 = mfma_bf16(ldg8(A + (size_t)lrow * K + k0), bfr, acc0);
    acc1 = mfma_bf16(ldg8(A + (size_t)(16 + lrow) * K + k0), bfr, acc1);
  }
  float bj = bias[j];
#pragma unroll
  for (int r = 0; r < 4; ++r) {
    int mA = g * 4 + r, mB = 16 + g * 4 + r;
    float vA = acc0[r] + bj, vB = acc1[r] + bj;
    if (outbf) {
      obf[(size_t)mA * N + j] = f2bf(vA);
      obf[(size_t)mB * N + j] = f2bf(vB);
    } else {
      of[(size_t)mA * N + j] = vA;
      of[(size_t)mB * N + j] = vB;
    }
  }
}

// ---------------- bilinear upsample + min-max norm ----------------
__global__ __launch_bounds__(256) void k_up(
    const float* __restrict__ y3g, float* __restrict__ out) {
  __shared__ float y3[256];
  __shared__ float red[8];
  int b = blockIdx.x, t = threadIdx.x;
  y3[t] = y3g[(size_t)b * 256 + t];
  __syncthreads();
  float vals[4];
  float mn = 3.0e38f, mx = -3.0e38f;
#pragma unroll
  for (int p2 = 0; p2 < 4; ++p2) {
    int p = t * 4 + p2;
    int i = p >> 6, jj = p & 63;
    float sy = fmaxf((float)i * 0.5f - 0.25f, 0.0f);
    int y0 = (int)sy; float fy = sy - (float)y0;
    int y1i = min(y0 + 1, 7);
    float sx = fmaxf((float)jj * 0.5f - 0.25f, 0.0f);
    int x0 = (int)sx; float fx = sx - (float)x0;
    int x1 = min(x0 + 1, 31);
    float v00 = y3[y0 * 32 + x0], v01 = y3[y0 * 32 + x1];
    float v10 = y3[y1i * 32 + x0], v11 = y3[y1i * 32 + x1];
    float v = (1.f - fy) * ((1.f - fx) * v00 + fx * v01)
            +        fy  * ((1.f - fx) * v10 + fx * v11);
    vals[p2] = v;
    mn = fminf(mn, v); mx = fmaxf(mx, v);
  }
#pragma unroll
  for (int off = 32; off; off >>= 1) {
    mn = fminf(mn, __shfl_xor(mn, off, 64));
    mx = fmaxf(mx, __shfl_xor(mx, off, 64));
  }
  int wv = t >> 6;
  if ((t & 63) == 0) { red[wv] = mn; red[4 + wv] = mx; }
  __syncthreads();
  mn = fminf(fminf(red[0], red[1]), fminf(red[2], red[3]));
  mx = fmaxf(fmaxf(red[4], red[5]), fmaxf(red[6], red[7]));
  float inv = 1.f / (mx - mn + 1e-8f);
#pragma unroll
  for (int p2 = 0; p2 < 4; ++p2)
    out[(size_t)b * 1024 + t * 4 + p2] = (vals[p2] - mn) * inv;
}

// ---------------- launch ----------------
extern "C" void kernel_launch(void* const* d_in, const int* in_sizes, int n_in,
                              void* d_out, int out_size, void* d_ws, size_t ws_size,
                              hipStream_t stream) {
  const float* x     = (const float*)d_in[0];
  const float* W_emb = (const float*)d_in[1];
  const float* b_emb = (const float*)d_in[2];
  const float* Wq    = (const float*)d_in[3];
  const float* bq    = (const float*)d_in[4];
  const float* Wk    = (const float*)d_in[5];
  const float* bk    = (const float*)d_in[6];
  const float* Wv    = (const float*)d_in[7];
  const float* bv    = (const float*)d_in[8];
  const float* Wo    = (const float*)d_in[9];
  const float* bo    = (const float*)d_in[10];
  const float* W_un  = (const float*)d_in[11];
  const float* b_un  = (const float*)d_in[12];
  const float* W1    = (const float*)d_in[13];
  const float* b1    = (const float*)d_in[14];
  const float* W2    = (const float*)d_in[15];
  const float* b2    = (const float*)d_in[16];
  const float* W3    = (const float*)d_in[17];
  const float* b3    = (const float*)d_in[18];

  char* ws = (char*)d_ws;
  unsigned short* hbf = (unsigned short*)(ws + 0);
  unsigned short* q   = (unsigned short*)(ws + 16777216);
  unsigned short* k   = (unsigned short*)(ws + 33554432);
  unsigned short* vT  = (unsigned short*)(ws + 50331648);
  unsigned short* wT  = (unsigned short*)(ws + 67108864);
  unsigned short* woT = (unsigned short*)(ws + 68681728);

  float*          xa   = (float*)(ws + 16777216);
  unsigned short* xabf = (unsigned short*)(ws + 16777216 + 65536);
  float*          y3   = (float*)(ws + 16777216 + 98304);
  unsigned short* w1T  = (unsigned short*)(ws + 33554432);
  unsigned short* w2T  = (unsigned short*)(ws + 35651584);
  unsigned short* w3T  = (unsigned short*)(ws + 37748736);
  unsigned short* y1bf = (unsigned short*)(ws + 38010880);
  unsigned short* y2bf = (unsigned short*)(ws + 38141952);

  float* out_y  = (float*)d_out;            // [32,1,16,64]
  float* out_xa = ((float*)d_out) + 32768;  // [32,512,1]

  k_transpose4<<<dim3(16, 16, 4), dim3(32, 8), 0, stream>>>(Wq, Wk, Wv, Wo, wT);

  k_embed<<<dim3(2048), dim3(256), 0, stream>>>(x, W_emb, b_emb, hbf);

  k_mm128<0><<<dim3(1536), dim3(256), 0, stream>>>(
      hbf, wT, bq, bk, bv, nullptr, q, k, vT, nullptr, 12);

  k_attn<<<dim3(512), dim3(512), 0, stream>>>(q, k, vT, hbf /* o reuses h */);

  k_transpose<<<dim3(64, 16), dim3(32, 8), 0, stream>>>(W1, w1T, 512, 2048);
  k_transpose<<<dim3(16, 64), dim3(32, 8), 0, stream>>>(W2, w2T, 2048, 512);
  k_transpose<<<dim3(8, 16),  dim3(32, 8), 0, stream>>>(W3, w3T, 512, 256);

  k_zero<<<dim3(64), dim3(256), 0, stream>>>(xa);

  k_mm128<1><<<dim3(512), dim3(256), 0, stream>>>(
      hbf, woT, bo, nullptr, nullptr, W_un, nullptr, nullptr, nullptr, xa, 4);

  k_xa_fin<<<dim3(64), dim3(256), 0, stream>>>(xa, b_un, out_xa, xabf);

  k_ffmm<<<dim3(32), dim3(256), 0, stream>>>(xabf, w1T, b1, 512, 2048, 1, y1bf, nullptr);
  k_ffmm<<<dim3(8),  dim3(256), 0, stream>>>(y1bf, w2T, b2, 2048, 512, 1, y2bf, nullptr);
  k_ffmm<<<dim3(4),  dim3(256), 0, stream>>>(y2bf, w3T, b3, 512, 256, 0, nullptr, y3);

  k_up<<<dim3(B_), dim3(256), 0, stream>>>(y3, out_y);
}

// Round 7
// 181.858 us; speedup vs baseline: 3.4073x; 1.0111x over previous
//
#include <hip/hip_runtime.h>

#define B_  32
#define N_  512
#define D_  512
#define H_  8
#define DH_ 64
#define M_  (B_*N_)   // 16384

typedef __attribute__((ext_vector_type(4))) float          f32x4;
typedef __attribute__((ext_vector_type(4))) unsigned short us4;
typedef __attribute__((ext_vector_type(8))) unsigned short us8;
typedef __attribute__((ext_vector_type(8))) __bf16         bf16x8;

__device__ __forceinline__ f32x4 mfma_bf16(us8 a, us8 b, f32x4 c) {
  return __builtin_amdgcn_mfma_f32_16x16x32_bf16(
      __builtin_bit_cast(bf16x8, a), __builtin_bit_cast(bf16x8, b), c, 0, 0, 0);
}

__device__ __forceinline__ unsigned short f2bf(float f) {  // hw RNE cvt
  return __builtin_bit_cast(unsigned short, (__bf16)f);
}

__device__ __forceinline__ float fexp2(float x) {  // raw v_exp_f32 (args bounded <=0, > -126)
  float r;
  asm("v_exp_f32 %0, %1" : "=v"(r) : "v"(x));
  return r;
}

__device__ __forceinline__ us8 ldg8(const unsigned short* p) {
  return *reinterpret_cast<const us8*>(p);
}

typedef const unsigned int __attribute__((address_space(1)))* gas_ptr;
typedef unsigned int __attribute__((address_space(3)))* las_ptr;

__device__ __forceinline__ void gload16(const unsigned short* src, unsigned short* ldsdst) {
  __builtin_amdgcn_global_load_lds((gas_ptr)(const void*)src, (las_ptr)(void*)ldsdst, 16, 0, 0);
}

// ---------------- 4x same-shape [512,512] transpose fp32 -> bf16 (Wq,Wk,Wv,Wo) ----------------
__global__ __launch_bounds__(256) void k_transpose4(
    const float* __restrict__ Wq, const float* __restrict__ Wk,
    const float* __restrict__ Wv, const float* __restrict__ Wo,
    unsigned short* __restrict__ dst) {
  __shared__ float t[32][33];
  int z = blockIdx.z;
  const float* src = (z == 0) ? Wq : (z == 1) ? Wk : (z == 2) ? Wv : Wo;
  unsigned short* out = dst + (size_t)z * (512 * 512);
  int c0 = blockIdx.x * 32, r0 = blockIdx.y * 32;
  int tx = threadIdx.x, ty = threadIdx.y;
  for (int yy = ty; yy < 32; yy += 8)
    t[yy][tx] = src[(size_t)(r0 + yy) * 512 + c0 + tx];
  __syncthreads();
  for (int yy = ty; yy < 32; yy += 8)
    out[(size_t)(c0 + yy) * 512 + r0 + tx] = f2bf(t[tx][yy]);
}

// ---------------- generic transpose fp32 [R][C] -> bf16 [C][R] ----------------
__global__ __launch_bounds__(256) void k_transpose(
    const float* __restrict__ src, unsigned short* __restrict__ dst, int R, int C) {
  __shared__ float t[32][33];
  int c0 = blockIdx.x * 32, r0 = blockIdx.y * 32;
  int tx = threadIdx.x, ty = threadIdx.y;
  for (int yy = ty; yy < 32; yy += 8)
    t[yy][tx] = src[(size_t)(r0 + yy) * C + c0 + tx];
  __syncthreads();
  for (int yy = ty; yy < 32; yy += 8)
    dst[(size_t)(c0 + yy) * R + r0 + tx] = f2bf(t[tx][yy]);
}

// ---------------- embed (vectorized x4) ----------------
__global__ __launch_bounds__(256) void k_embed(
    const float* __restrict__ x, const float* __restrict__ W_emb,
    const float* __restrict__ b_emb, unsigned short* __restrict__ hbf) {
  for (int idx = blockIdx.x * 256 + threadIdx.x; idx < M_ * 128; idx += 2048 * 256) {
    int m = idx >> 7, d4 = idx & 127;
    int n = m & (N_ - 1);
    float xv = x[m];
    f32x4 wv = *reinterpret_cast<const f32x4*>(W_emb + (size_t)n * D_ + d4 * 4);
    f32x4 bv = *reinterpret_cast<const f32x4*>(b_emb + (size_t)n * D_ + d4 * 4);
    us4 o;
#pragma unroll
    for (int e = 0; e < 4; ++e) o[e] = f2bf(xv * wv[e] + bv[e]);
    *reinterpret_cast<us4*>(hbf + (size_t)m * D_ + d4 * 4) = o;
  }
}

// ---------------- 128x128x64 LDS-staged MFMA GEMM, XOR-swizzled LDS, counted-vmcnt ----------------
template<int EPI>
__global__ __launch_bounds__(256, 2) void k_mm128(
    const unsigned short* __restrict__ A,
    const unsigned short* __restrict__ Bt,
    const float* __restrict__ bias0, const float* __restrict__ bias1,
    const float* __restrict__ bias2,
    const float* __restrict__ Wun,
    unsigned short* __restrict__ o0, unsigned short* __restrict__ o1,
    unsigned short* __restrict__ o2,
    float* __restrict__ xa,
    int ntiles) {
  __shared__ __align__(16) unsigned short lds[2][2 * 128 * 64];
  const int K = 512;
  int nwg = gridDim.x;
  int cpx = nwg >> 3;
  int wgid = ((int)blockIdx.x & 7) * cpx + ((int)blockIdx.x >> 3);
  int mt = wgid / ntiles, nt = wgid - mt * ntiles;
  int m0 = mt * 128, n0 = nt * 128;
  int tid = threadIdx.x, wave = tid >> 6, lane = tid & 63;
  int lrow = lane & 15, g = lane >> 4;
  int wr = wave >> 1, wc = wave & 1;

  f32x4 acc[4][4];
#pragma unroll
  for (int i = 0; i < 4; ++i)
#pragma unroll
    for (int j = 0; j < 4; ++j) acc[i][j] = (f32x4){0.f, 0.f, 0.f, 0.f};

  int rseg_base = wave * 8 + (lane >> 3);
  int coff = (((lane & 7) ^ (lane >> 3)) << 3);   // swizzled source chunk

  // prologue: stage tile 0 -> buf0 (no drain; first loop iteration's vmcnt(8) covers it)
#pragma unroll
  for (int i = 0; i < 4; ++i) {
    int rs = i * 32 + rseg_base;
    gload16(A  + (size_t)(m0 + rs) * K + coff, &lds[0][(i * 4 + wave) * 512]);
    gload16(Bt + (size_t)(n0 + rs) * K + coff, &lds[0][128 * 64 + (i * 4 + wave) * 512]);
  }

  for (int ks = 0; ks < 8; ++ks) {
    if (ks < 7) {
      int k0 = (ks + 1) * 64;
      int buf = (ks + 1) & 1;
#pragma unroll
      for (int i = 0; i < 4; ++i) {
        int rs = i * 32 + rseg_base;
        gload16(A  + (size_t)(m0 + rs) * K + k0 + coff, &lds[buf][(i * 4 + wave) * 512]);
        gload16(Bt + (size_t)(n0 + rs) * K + k0 + coff, &lds[buf][128 * 64 + (i * 4 + wave) * 512]);
      }
      asm volatile("s_waitcnt vmcnt(8)" ::: "memory");  // tile ks staged; ks+1 stays in flight
    } else {
      asm volatile("s_waitcnt vmcnt(0)" ::: "memory");
    }
    __builtin_amdgcn_sched_barrier(0);
    __builtin_amdgcn_s_barrier();
    __builtin_amdgcn_sched_barrier(0);

    const char* la = (const char*)&lds[ks & 1][0];
    const char* lb = la + 128 * 64 * 2;
    int sw = (lrow & 7) << 4;
#pragma unroll
    for (int kk = 0; kk < 2; ++kk) {
      us8 aF[4], bF[4];
#pragma unroll
      for (int mi = 0; mi < 4; ++mi)
        aF[mi] = *reinterpret_cast<const us8*>(
            la + (wr * 64 + mi * 16 + lrow) * 128 + ((kk * 64 + g * 16) ^ sw));
#pragma unroll
      for (int ni = 0; ni < 4; ++ni)
        bF[ni] = *reinterpret_cast<const us8*>(
            lb + (wc * 64 + ni * 16 + lrow) * 128 + ((kk * 64 + g * 16) ^ sw));
#pragma unroll
      for (int mi = 0; mi < 4; ++mi)
#pragma unroll
        for (int ni = 0; ni < 4; ++ni)
          acc[mi][ni] = mfma_bf16(aF[mi], bF[ni], acc[mi][ni]);
    }
    if (ks < 7) {  // guard buf[(ks)&1]... re-stage at ks+1 targets buf[ks&1]: all waves' reads done
      __builtin_amdgcn_sched_barrier(0);
      __builtin_amdgcn_s_barrier();
    }
  }

  if (EPI == 0) {
#pragma unroll
    for (int ni = 0; ni < 4; ++ni) {
      int j = n0 + wc * 64 + ni * 16 + lrow;
      int which = j >> 9, jj = j & 511, head = jj >> 6, dh = jj & 63;
      float bj = (which == 0 ? bias0 : which == 1 ? bias1 : bias2)[jj];
      unsigned short* base = (which == 0) ? o0 : (which == 1) ? o1 : o2;
#pragma unroll
      for (int mi = 0; mi < 4; ++mi) {
#pragma unroll
        for (int r = 0; r < 4; ++r) {
          int m = m0 + wr * 64 + mi * 16 + g * 4 + r;
          int b = m >> 9, n = m & 511;
          unsigned short v = f2bf(acc[mi][ni][r] + bj);
          if (which < 2) base[((size_t)(b * 8 + head) * 512 + n) * 64 + dh] = v;
          else           base[((size_t)(b * 8 + head) * 64 + dh) * 512 + n] = v;
        }
      }
    }
  } else {
    float part[16];
#pragma unroll
    for (int i = 0; i < 16; ++i) part[i] = 0.f;
#pragma unroll
    for (int ni = 0; ni < 4; ++ni) {
      int j = n0 + wc * 64 + ni * 16 + lrow;
      float bj = bias0[j];
#pragma unroll
      for (int mi = 0; mi < 4; ++mi) {
#pragma unroll
        for (int r = 0; r < 4; ++r) {
          int m = m0 + wr * 64 + mi * 16 + g * 4 + r;
          int n = m & 511;
          part[mi * 4 + r] += (acc[mi][ni][r] + bj) * Wun[(size_t)n * 512 + j];
        }
      }
    }
#pragma unroll
    for (int off = 1; off < 16; off <<= 1)
#pragma unroll
      for (int t2 = 0; t2 < 16; ++t2)
        part[t2] += __shfl_xor(part[t2], off, 64);
    if (lrow == 0) {
#pragma unroll
      for (int mi = 0; mi < 4; ++mi)
#pragma unroll
        for (int r = 0; r < 4; ++r)
          atomicAdd(&xa[m0 + wr * 64 + mi * 16 + g * 4 + r], part[mi * 4 + r]);
    }
  }
}

// ---------------- flash attention: 2 blocks per (b,h), counted-vmcnt pipeline ----------------
__global__ __launch_bounds__(512, 4) void k_attn(
    const unsigned short* __restrict__ q, const unsigned short* __restrict__ kk,
    const unsigned short* __restrict__ vT, unsigned short* __restrict__ o) {
  __shared__ __align__(16) unsigned short kbuf[2][4096];
  __shared__ __align__(16) unsigned short vbuf[2][4096];
  __shared__ __align__(16) unsigned short pbuf[8][1024];
  int bh = blockIdx.x >> 1, half = blockIdx.x & 1;
  int b = bh >> 3, h = bh & 7;
  const unsigned short* qh = q  + (size_t)bh * (N_ * DH_);
  const unsigned short* kh = kk + (size_t)bh * (N_ * DH_);
  const unsigned short* vh = vT + (size_t)bh * (DH_ * N_);
  int w = threadIdx.x >> 6, lane = threadIdx.x & 63;
  int lr = lane & 15, g = lane >> 4;
  const float cexp = 0.18033688011112042f;   // log2(e)/8
  const float THRraw = 44.35f;               // 8 / cexp

  us8 bq[2][2];
#pragma unroll
  for (int tt = 0; tt < 2; ++tt) {
    const unsigned short* qrow = qh + (size_t)(half * 256 + w * 32 + tt * 16 + lr) * DH_;
    bq[tt][0] = ldg8(qrow + g * 8);
    bq[tt][1] = ldg8(qrow + 32 + g * 8);
  }

  f32x4 oacc[2][4];
#pragma unroll
  for (int tt = 0; tt < 2; ++tt)
#pragma unroll
    for (int db = 0; db < 4; ++db) oacc[tt][db] = (f32x4){0.f, 0.f, 0.f, 0.f};
  float mrun[2] = {-3.0e38f, -3.0e38f};
  float lrun[2] = {0.f, 0.f};

  int k_mcl = w >> 1, k_kk = w & 1;
  const unsigned short* ksrc_base = kh + (size_t)(k_mcl * 16 + lr) * DH_ + k_kk * 32 + g * 8;
  const unsigned short* vsrc_base = vh + (size_t)(k_mcl * 16 + lr) * N_  + k_kk * 32 + g * 8;

  gload16(ksrc_base, &kbuf[0][w * 512]);
  gload16(vsrc_base, &vbuf[0][w * 512]);

  char* pw = (char*)&pbuf[w][0];

  for (int mb8 = 0; mb8 < 8; ++mb8) {
    int cur = mb8 & 1;
    if (mb8 < 7) {
      gload16(ksrc_base + (size_t)(mb8 + 1) * 64 * DH_, &kbuf[cur ^ 1][w * 512]);
      gload16(vsrc_base + (mb8 + 1) * 64,               &vbuf[cur ^ 1][w * 512]);
      asm volatile("s_waitcnt vmcnt(2)" ::: "memory");  // block mb8 staged; mb8+1 in flight
    } else {
      asm volatile("s_waitcnt vmcnt(0)" ::: "memory");
    }
    __builtin_amdgcn_sched_barrier(0);
    __builtin_amdgcn_s_barrier();
    __builtin_amdgcn_sched_barrier(0);

    const char* kb = (const char*)&kbuf[cur][0];
    const char* vb = (const char*)&vbuf[cur][0];

#pragma unroll
    for (int tt = 0; tt < 2; ++tt) {
      f32x4 s[4];
#pragma unroll
      for (int mc_l = 0; mc_l < 4; ++mc_l) {
        f32x4 a = (f32x4){0.f, 0.f, 0.f, 0.f};
        a = mfma_bf16(*(const us8*)(kb + (mc_l * 2 + 0) * 1024 + lane * 16), bq[tt][0], a);
        a = mfma_bf16(*(const us8*)(kb + (mc_l * 2 + 1) * 1024 + lane * 16), bq[tt][1], a);
        s[mc_l] = a;
      }
      float pmax = fmaxf(fmaxf(s[0][0], s[0][1]), fmaxf(s[0][2], s[0][3]));
#pragma unroll
      for (int mc_l = 1; mc_l < 4; ++mc_l)
        pmax = fmaxf(pmax, fmaxf(fmaxf(s[mc_l][0], s[mc_l][1]), fmaxf(s[mc_l][2], s[mc_l][3])));
      pmax = fmaxf(pmax, __shfl_xor(pmax, 16, 64));
      pmax = fmaxf(pmax, __shfl_xor(pmax, 32, 64));
      if (__any(pmax > mrun[tt] + THRraw)) {   // defer-max (T13)
        float mnew = fmaxf(mrun[tt], pmax);
        float rs = fexp2((mrun[tt] - mnew) * cexp);
        mrun[tt] = mnew;
        lrun[tt] *= rs;
#pragma unroll
        for (int db = 0; db < 4; ++db) oacc[tt][db] *= rs;
      }
      float mcur = mrun[tt];
      float lsum = 0.f;
#pragma unroll
      for (int mc_l = 0; mc_l < 4; ++mc_l) {
#pragma unroll
        for (int r = 0; r < 4; ++r) {
          float p = fexp2((s[mc_l][r] - mcur) * cexp);
          s[mc_l][r] = p;
          lsum += p;
        }
      }
      lsum += __shfl_xor(lsum, 16, 64);
      lsum += __shfl_xor(lsum, 32, 64);
      lrun[tt] += lsum;
#pragma unroll
      for (int mc_l = 0; mc_l < 4; ++mc_l) {
        uint2 u;
        u.x = (unsigned)f2bf(s[mc_l][0]) | ((unsigned)f2bf(s[mc_l][1]) << 16);
        u.y = (unsigned)f2bf(s[mc_l][2]) | ((unsigned)f2bf(s[mc_l][3]) << 16);
        unsigned off = (unsigned)((mc_l >> 1) * 1024 + (((mc_l & 1) << 1) | (g >> 1)) * 256
                                  + lr * 16 + (g & 1) * 8);
        *reinterpret_cast<uint2*>(pw + off) = u;
      }
#pragma unroll
      for (int ks = 0; ks < 2; ++ks) {
        us8 bp = *(const us8*)(pw + ks * 1024 + lane * 16);
#pragma unroll
        for (int db = 0; db < 4; ++db) {
          us8 av = *(const us8*)(vb + (db * 2 + ks) * 1024 + lane * 16);
          oacc[tt][db] = mfma_bf16(av, bp, oacc[tt][db]);
        }
      }
    }
    if (mb8 < 7) {
      __builtin_amdgcn_sched_barrier(0);
      __builtin_amdgcn_s_barrier();
    }
  }

#pragma unroll
  for (int tt = 0; tt < 2; ++tt) {
    float inv = 1.f / lrun[tt];
#pragma unroll
    for (int db = 0; db < 4; ++db) {
      uint2 u;
      u.x = (unsigned)f2bf(oacc[tt][db][0] * inv) | ((unsigned)f2bf(oacc[tt][db][1] * inv) << 16);
      u.y = (unsigned)f2bf(oacc[tt][db][2] * inv) | ((unsigned)f2bf(oacc[tt][db][3] * inv) << 16);
      unsigned off = (unsigned)(lr * 128 + ((db * 32 + g * 8) ^ ((lr & 7) << 4)));
      *reinterpret_cast<uint2*>(pw + off) = u;
    }
    int n_l = lane >> 2;
#pragma unroll
    for (int hh = 0; hh < 2; ++hh) {
      int c16 = (lane & 3) + 4 * hh;
      us8 vv = *(const us8*)(pw + n_l * 128 + ((c16 ^ (n_l & 7)) << 4));
      *reinterpret_cast<us8*>(o + ((size_t)(b * 512 + half * 256 + w * 32 + tt * 16 + n_l)) * D_
                               + h * 64 + c16 * 8) = vv;
    }
  }
}

// ---------------- zero xa ----------------
__global__ __launch_bounds__(256) void k_zero(float* __restrict__ p) {
  p[blockIdx.x * 256 + threadIdx.x] = 0.f;
}

// ---------------- xa finish ----------------
__global__ __launch_bounds__(256) void k_xa_fin(
    const float* __restrict__ xa, const float* __restrict__ bun,
    float* __restrict__ out_xa, unsigned short* __restrict__ xabf) {
  int m = blockIdx.x * 256 + threadIdx.x;
  float v = xa[m] + bun[m & (N_ - 1)];
  out_xa[m] = v;
  xabf[m] = f2bf(v);
}

// ---------------- small M=32 MFMA GEMM for ff layers ----------------
__global__ __launch_bounds__(256) void k_ffmm(
    const unsigned short* __restrict__ A,
    const unsigned short* __restrict__ Bt,
    const float* __restrict__ bias, int K, int N, int outbf,
    unsigned short* __restrict__ obf, float* __restrict__ of) {
  int wave = threadIdx.x >> 6, lane = threadIdx.x & 63;
  int lrow = lane & 15, g = lane >> 4;
  int j = blockIdx.x * 64 + wave * 16 + lrow;
  f32x4 acc0 = (f32x4){0.f, 0.f, 0.f, 0.f}, acc1 = acc0;
  const unsigned short* brow = Bt + (size_t)j * K;
  for (int k0 = g * 8; k0 < K; k0 += 32) {
    us8 bfr = ldg8(brow + k0);
    acc0 = mfma_bf16(ldg8(A + (size_t)lrow * K + k0), bfr, acc0);
    acc1 = mfma_bf16(ldg8(A + (size_t)(16 + lrow) * K + k0), bfr, acc1);
  }
  float bj = bias[j];
#pragma unroll
  for (int r = 0; r < 4; ++r) {
    int mA = g * 4 + r, mB = 16 + g * 4 + r;
    float vA = acc0[r] + bj, vB = acc1[r] + bj;
    if (outbf) {
      obf[(size_t)mA * N + j] = f2bf(vA);
      obf[(size_t)mB * N + j] = f2bf(vB);
    } else {
      of[(size_t)mA * N + j] = vA;
      of[(size_t)mB * N + j] = vB;
    }
  }
}

// ---------------- bilinear upsample + min-max norm ----------------
__global__ __launch_bounds__(256) void k_up(
    const float* __restrict__ y3g, float* __restrict__ out) {
  __shared__ float y3[256];
  __shared__ float red[8];
  int b = blockIdx.x, t = threadIdx.x;
  y3[t] = y3g[(size_t)b * 256 + t];
  __syncthreads();
  float vals[4];
  float mn = 3.0e38f, mx = -3.0e38f;
#pragma unroll
  for (int p2 = 0; p2 < 4; ++p2) {
    int p = t * 4 + p2;
    int i = p >> 6, jj = p & 63;
    float sy = fmaxf((float)i * 0.5f - 0.25f, 0.0f);
    int y0 = (int)sy; float fy = sy - (float)y0;
    int y1i = min(y0 + 1, 7);
    float sx = fmaxf((float)jj * 0.5f - 0.25f, 0.0f);
    int x0 = (int)sx; float fx = sx - (float)x0;
    int x1 = min(x0 + 1, 31);
    float v00 = y3[y0 * 32 + x0], v01 = y3[y0 * 32 + x1];
    float v10 = y3[y1i * 32 + x0], v11 = y3[y1i * 32 + x1];
    float v = (1.f - fy) * ((1.f - fx) * v00 + fx * v01)
            +        fy  * ((1.f - fx) * v10 + fx * v11);
    vals[p2] = v;
    mn = fminf(mn, v); mx = fmaxf(mx, v);
  }
#pragma unroll
  for (int off = 32; off; off >>= 1) {
    mn = fminf(mn, __shfl_xor(mn, off, 64));
    mx = fmaxf(mx, __shfl_xor(mx, off, 64));
  }
  int wv = t >> 6;
  if ((t & 63) == 0) { red[wv] = mn; red[4 + wv] = mx; }
  __syncthreads();
  mn = fminf(fminf(red[0], red[1]), fminf(red[2], red[3]));
  mx = fmaxf(fmaxf(red[4], red[5]), fmaxf(red[6], red[7]));
  float inv = 1.f / (mx - mn + 1e-8f);
#pragma unroll
  for (int p2 = 0; p2 < 4; ++p2)
    out[(size_t)b * 1024 + t * 4 + p2] = (vals[p2] - mn) * inv;
}

// ---------------- launch ----------------
extern "C" void kernel_launch(void* const* d_in, const int* in_sizes, int n_in,
                              void* d_out, int out_size, void* d_ws, size_t ws_size,
                              hipStream_t stream) {
  const float* x     = (const float*)d_in[0];
  const float* W_emb = (const float*)d_in[1];
  const float* b_emb = (const float*)d_in[2];
  const float* Wq    = (const float*)d_in[3];
  const float* bq    = (const float*)d_in[4];
  const float* Wk    = (const float*)d_in[5];
  const float* bk    = (const float*)d_in[6];
  const float* Wv    = (const float*)d_in[7];
  const float* bv    = (const float*)d_in[8];
  const float* Wo    = (const float*)d_in[9];
  const float* bo    = (const float*)d_in[10];
  const float* W_un  = (const float*)d_in[11];
  const float* b_un  = (const float*)d_in[12];
  const float* W1    = (const float*)d_in[13];
  const float* b1    = (const float*)d_in[14];
  const float* W2    = (const float*)d_in[15];
  const float* b2    = (const float*)d_in[16];
  const float* W3    = (const float*)d_in[17];
  const float* b3    = (const float*)d_in[18];

  char* ws = (char*)d_ws;
  unsigned short* hbf = (unsigned short*)(ws + 0);
  unsigned short* q   = (unsigned short*)(ws + 16777216);
  unsigned short* k   = (unsigned short*)(ws + 33554432);
  unsigned short* vT  = (unsigned short*)(ws + 50331648);
  unsigned short* wT  = (unsigned short*)(ws + 67108864);
  unsigned short* woT = (unsigned short*)(ws + 68681728);

  float*          xa   = (float*)(ws + 16777216);
  unsigned short* xabf = (unsigned short*)(ws + 16777216 + 65536);
  float*          y3   = (float*)(ws + 16777216 + 98304);
  unsigned short* w1T  = (unsigned short*)(ws + 33554432);
  unsigned short* w2T  = (unsigned short*)(ws + 35651584);
  unsigned short* w3T  = (unsigned short*)(ws + 37748736);
  unsigned short* y1bf = (unsigned short*)(ws + 38010880);
  unsigned short* y2bf = (unsigned short*)(ws + 38141952);

  float* out_y  = (float*)d_out;            // [32,1,16,64]
  float* out_xa = ((float*)d_out) + 32768;  // [32,512,1]

  k_transpose4<<<dim3(16, 16, 4), dim3(32, 8), 0, stream>>>(Wq, Wk, Wv, Wo, wT);

  k_embed<<<dim3(2048), dim3(256), 0, stream>>>(x, W_emb, b_emb, hbf);

  k_mm128<0><<<dim3(1536), dim3(256), 0, stream>>>(
      hbf, wT, bq, bk, bv, nullptr, q, k, vT, nullptr, 12);

  k_attn<<<dim3(512), dim3(512), 0, stream>>>(q, k, vT, hbf /* o reuses h */);

  k_transpose<<<dim3(64, 16), dim3(32, 8), 0, stream>>>(W1, w1T, 512, 2048);
  k_transpose<<<dim3(16, 64), dim3(32, 8), 0, stream>>>(W2, w2T, 2048, 512);
  k_transpose<<<dim3(8, 16),  dim3(32, 8), 0, stream>>>(W3, w3T, 512, 256);

  k_zero<<<dim3(64), dim3(256), 0, stream>>>(xa);

  k_mm128<1><<<dim3(512), dim3(256), 0, stream>>>(
      hbf, woT, bo, nullptr, nullptr, W_un, nullptr, nullptr, nullptr, xa, 4);

  k_xa_fin<<<dim3(64), dim3(256), 0, stream>>>(xa, b_un, out_xa, xabf);

  k_ffmm<<<dim3(32), dim3(256), 0, stream>>>(xabf, w1T, b1, 512, 2048, 1, y1bf, nullptr);
  k_ffmm<<<dim3(8),  dim3(256), 0, stream>>>(y1bf, w2T, b2, 2048, 512, 1, y2bf, nullptr);
  k_ffmm<<<dim3(4),  dim3(256), 0, stream>>>(y2bf, w3T, b3, 512, 256, 0, nullptr, y3);

  k_up<<<dim3(B_), dim3(256), 0, stream>>>(y3, out_y);
}

// Round 8
// 132.801 us; speedup vs baseline: 4.6660x; 1.3694x over previous
//
#include <hip/hip_runtime.h>

#define B_  32
#define N_  512
#define D_  512
#define H_  8
#define DH_ 64
#define M_  (B_*N_)   // 16384

typedef __attribute__((ext_vector_type(4))) float          f32x4;
typedef __attribute__((ext_vector_type(4))) unsigned short us4;
typedef __attribute__((ext_vector_type(8))) unsigned short us8;
typedef __attribute__((ext_vector_type(8))) __bf16         bf16x8;

__device__ __forceinline__ f32x4 mfma_bf16(us8 a, us8 b, f32x4 c) {
  return __builtin_amdgcn_mfma_f32_16x16x32_bf16(
      __builtin_bit_cast(bf16x8, a), __builtin_bit_cast(bf16x8, b), c, 0, 0, 0);
}

__device__ __forceinline__ unsigned short f2bf(float f) {  // hw RNE cvt
  return __builtin_bit_cast(unsigned short, (__bf16)f);
}

__device__ __forceinline__ float bf2f(unsigned short u) {
  return __builtin_bit_cast(float, (unsigned)u << 16);
}

__device__ __forceinline__ float fexp2(float x) {  // raw v_exp_f32 (args bounded <=0, > -126)
  float r;
  asm("v_exp_f32 %0, %1" : "=v"(r) : "v"(x));
  return r;
}

__device__ __forceinline__ us8 ldg8(const unsigned short* p) {
  return *reinterpret_cast<const us8*>(p);
}

typedef const unsigned int __attribute__((address_space(1)))* gas_ptr;
typedef unsigned int __attribute__((address_space(3)))* las_ptr;

__device__ __forceinline__ void gload16(const unsigned short* src, unsigned short* ldsdst) {
  __builtin_amdgcn_global_load_lds((gas_ptr)(const void*)src, (las_ptr)(void*)ldsdst, 16, 0, 0);
}

// ---------------- cast fp32 -> bf16: P0=[W_emb;b_emb], WunBf, WoBf ----------------
__global__ __launch_bounds__(256) void k_cast(
    const float* __restrict__ W_emb, const float* __restrict__ b_emb,
    const float* __restrict__ Wun, const float* __restrict__ Wo,
    unsigned short* __restrict__ P0, unsigned short* __restrict__ WunBf,
    unsigned short* __restrict__ WoBf) {
  int idx = blockIdx.x * 256 + threadIdx.x;   // 0..262143, 4 elems each
  const float* src; unsigned short* dst; int off;
  if (idx < 65536)        { src = W_emb; dst = P0;          off = idx; }
  else if (idx < 131072)  { src = b_emb; dst = P0 + 262144; off = idx - 65536; }
  else if (idx < 196608)  { src = Wun;   dst = WunBf;       off = idx - 131072; }
  else                    { src = Wo;    dst = WoBf;        off = idx - 196608; }
  f32x4 v = *reinterpret_cast<const f32x4*>(src + (size_t)off * 4);
  us4 o;
#pragma unroll
  for (int e = 0; e < 4; ++e) o[e] = f2bf(v[e]);
  *reinterpret_cast<us4*>(dst + (size_t)off * 4) = o;
}

// ---------------- 3x [512,512] transpose fp32 -> bf16 (Wq,Wk,Wv) ----------------
__global__ __launch_bounds__(256) void k_transpose3(
    const float* __restrict__ Wq, const float* __restrict__ Wk,
    const float* __restrict__ Wv, unsigned short* __restrict__ dst) {
  __shared__ float t[32][33];
  int z = blockIdx.z;
  const float* src = (z == 0) ? Wq : (z == 1) ? Wk : Wv;
  unsigned short* out = dst + (size_t)z * (512 * 512);
  int c0 = blockIdx.x * 32, r0 = blockIdx.y * 32;
  int tx = threadIdx.x, ty = threadIdx.y;
  for (int yy = ty; yy < 32; yy += 8)
    t[yy][tx] = src[(size_t)(r0 + yy) * 512 + c0 + tx];
  __syncthreads();
  for (int yy = ty; yy < 32; yy += 8)
    out[(size_t)(c0 + yy) * 512 + r0 + tx] = f2bf(t[tx][yy]);
}

// ---------------- generic transpose fp32 [R][C] -> bf16 [C][R] ----------------
__global__ __launch_bounds__(256) void k_transpose(
    const float* __restrict__ src, unsigned short* __restrict__ dst, int R, int C) {
  __shared__ float t[32][33];
  int c0 = blockIdx.x * 32, r0 = blockIdx.y * 32;
  int tx = threadIdx.x, ty = threadIdx.y;
  for (int yy = ty; yy < 32; yy += 8)
    t[yy][tx] = src[(size_t)(r0 + yy) * C + c0 + tx];
  __syncthreads();
  for (int yy = ty; yy < 32; yy += 8)
    dst[(size_t)(c0 + yy) * R + r0 + tx] = f2bf(t[tx][yy]);
}

// ---------------- unified weight-prep GEMM (128x128x64 tiles, swizzled LDS) ----------------
// wgid < 96:  P1[1024][1536] = [W_emb;b_emb] @ [Wq|Wk|Wv]  (v-part transposed into vpre,
//             bias added to b_emb rows)
// wgid >= 96: wEff[512][512] = Wun @ Wo^T  (over j: wEff[n][d] = sum_j Wun[n][j] Wo[d][j])
__global__ __launch_bounds__(256, 2) void k_prep(
    const unsigned short* __restrict__ P0,    // [1024][512] bf16
    const unsigned short* __restrict__ wT,    // [1536][512] bf16 (Wq^T,Wk^T,Wv^T)
    const unsigned short* __restrict__ WunBf, // [512][512] bf16
    const unsigned short* __restrict__ WoBf,  // [512][512] bf16
    const float* __restrict__ bq, const float* __restrict__ bk,
    const float* __restrict__ bv,
    unsigned short* __restrict__ P1,          // [1024][1536] bf16
    unsigned short* __restrict__ vpre,        // [2][512][512] bf16
    unsigned short* __restrict__ wEff) {      // [512][512] bf16
  __shared__ __align__(16) unsigned short lds[2][2 * 128 * 64];
  const int K = 512;
  int nwg = gridDim.x;                        // 112
  int cpx = nwg >> 3;                         // 14
  int wgid = ((int)blockIdx.x & 7) * cpx + ((int)blockIdx.x >> 3);
  bool p1 = wgid < 96;
  int lid = p1 ? wgid : wgid - 96;
  int ntiles = p1 ? 12 : 4;
  const unsigned short* A  = p1 ? P0 : WunBf;
  const unsigned short* Bt = p1 ? wT : WoBf;
  int mt = lid / ntiles, nt = lid - mt * ntiles;
  int m0 = mt * 128, n0 = nt * 128;
  int tid = threadIdx.x, wave = tid >> 6, lane = tid & 63;
  int lrow = lane & 15, g = lane >> 4;
  int wr = wave >> 1, wc = wave & 1;

  f32x4 acc[4][4];
#pragma unroll
  for (int i = 0; i < 4; ++i)
#pragma unroll
    for (int j = 0; j < 4; ++j) acc[i][j] = (f32x4){0.f, 0.f, 0.f, 0.f};

  int rseg_base = wave * 8 + (lane >> 3);
  int coff = (((lane & 7) ^ (lane >> 3)) << 3);   // swizzled source chunk (rule #21)

#pragma unroll
  for (int i = 0; i < 4; ++i) {
    int rs = i * 32 + rseg_base;
    gload16(A  + (size_t)(m0 + rs) * K + coff, &lds[0][(i * 4 + wave) * 512]);
    gload16(Bt + (size_t)(n0 + rs) * K + coff, &lds[0][128 * 64 + (i * 4 + wave) * 512]);
  }
  __syncthreads();

  for (int ks = 0; ks < 8; ++ks) {
    if (ks < 7) {
      int k0 = (ks + 1) * 64;
      int buf = (ks + 1) & 1;
#pragma unroll
      for (int i = 0; i < 4; ++i) {
        int rs = i * 32 + rseg_base;
        gload16(A  + (size_t)(m0 + rs) * K + k0 + coff, &lds[buf][(i * 4 + wave) * 512]);
        gload16(Bt + (size_t)(n0 + rs) * K + k0 + coff, &lds[buf][128 * 64 + (i * 4 + wave) * 512]);
      }
    }
    const char* la = (const char*)&lds[ks & 1][0];
    const char* lb = la + 128 * 64 * 2;
    int sw = (lrow & 7) << 4;
#pragma unroll
    for (int kk = 0; kk < 2; ++kk) {
      us8 aF[4], bF[4];
#pragma unroll
      for (int mi = 0; mi < 4; ++mi)
        aF[mi] = *reinterpret_cast<const us8*>(
            la + (wr * 64 + mi * 16 + lrow) * 128 + ((kk * 64 + g * 16) ^ sw));
#pragma unroll
      for (int ni = 0; ni < 4; ++ni)
        bF[ni] = *reinterpret_cast<const us8*>(
            lb + (wc * 64 + ni * 16 + lrow) * 128 + ((kk * 64 + g * 16) ^ sw));
#pragma unroll
      for (int mi = 0; mi < 4; ++mi)
#pragma unroll
        for (int ni = 0; ni < 4; ++ni)
          acc[mi][ni] = mfma_bf16(aF[mi], bF[ni], acc[mi][ni]);
    }
    __syncthreads();
  }

  if (p1) {
#pragma unroll
    for (int ni = 0; ni < 4; ++ni) {
      int j = n0 + wc * 64 + ni * 16 + lrow;      // 0..1535
      int which = j >> 9, jj = j & 511;
      float bj = (which == 0 ? bq : which == 1 ? bk : bv)[jj];
#pragma unroll
      for (int mi = 0; mi < 4; ++mi) {
#pragma unroll
        for (int r = 0; r < 4; ++r) {
          int mrow = m0 + wr * 64 + mi * 16 + g * 4 + r;  // 0..1023
          int isB = mrow >> 9, n = mrow & 511;
          unsigned short v16 = f2bf(acc[mi][ni][r] + (isB ? bj : 0.f));
          if (which < 2) P1[(size_t)mrow * 1536 + j] = v16;
          else           vpre[(size_t)isB * 262144 + (size_t)jj * 512 + n] = v16;
        }
      }
    }
  } else {
#pragma unroll
    for (int ni = 0; ni < 4; ++ni) {
      int j = n0 + wc * 64 + ni * 16 + lrow;      // 0..511 (d)
#pragma unroll
      for (int mi = 0; mi < 4; ++mi) {
#pragma unroll
        for (int r = 0; r < 4; ++r) {
          int mrow = m0 + wr * 64 + mi * 16 + g * 4 + r;  // 0..511 (n)
          wEff[(size_t)mrow * 512 + j] = f2bf(acc[mi][ni][r]);
        }
      }
    }
  }
}

// ---------------- cb[n] = dot(Wun[n], bo) + b_un[n] ----------------
__global__ __launch_bounds__(256) void k_cb(
    const float* __restrict__ Wun, const float* __restrict__ bo,
    const float* __restrict__ bun, float* __restrict__ cb) {
  int n = blockIdx.x * 4 + (threadIdx.x >> 6);
  int lane = threadIdx.x & 63;
  const float* a = Wun + (size_t)n * 512 + lane * 8;
  const float* b = bo + lane * 8;
  f32x4 a0 = *reinterpret_cast<const f32x4*>(a);
  f32x4 a1 = *reinterpret_cast<const f32x4*>(a + 4);
  f32x4 b0 = *reinterpret_cast<const f32x4*>(b);
  f32x4 b1 = *reinterpret_cast<const f32x4*>(b + 4);
  float s = a0[0]*b0[0] + a0[1]*b0[1] + a0[2]*b0[2] + a0[3]*b0[3]
          + a1[0]*b1[0] + a1[1]*b1[1] + a1[2]*b1[2] + a1[3]*b1[3];
#pragma unroll
  for (int off = 32; off; off >>= 1) s += __shfl_xor(s, off, 64);
  if (lane == 0) cb[n] = s + bun[n];
}

// ---------------- elementwise QKV expansion: q = x*Aq + Bq etc ----------------
__global__ __launch_bounds__(512) void k_qkvgen(
    const float* __restrict__ x,              // [32][512]
    const unsigned short* __restrict__ P1,    // [1024][1536]
    const unsigned short* __restrict__ vpre,  // [2][512][512]
    unsigned short* __restrict__ q,
    unsigned short* __restrict__ k,
    unsigned short* __restrict__ vT) {
  int bh = blockIdx.x;                        // 0..255
  int b = bh >> 3, h = bh & 7;
  int tid = threadIdx.x;
  int r8 = tid >> 3;                          // 0..63
  int oct = tid & 7;                          // 0..7
  // q/k: rows n, cols dh
  for (int nb = 0; nb < 8; ++nb) {
    int n = nb * 64 + r8;
    float xv = x[b * 512 + n];
    int col = h * 64 + oct * 8;
    {
      us8 a = ldg8(P1 + (size_t)n * 1536 + col);
      us8 bb = ldg8(P1 + (size_t)(512 + n) * 1536 + col);
      us8 o8;
#pragma unroll
      for (int e = 0; e < 8; ++e) o8[e] = f2bf(xv * bf2f(a[e]) + bf2f(bb[e]));
      *reinterpret_cast<us8*>(q + ((size_t)(bh * 512 + n)) * 64 + oct * 8) = o8;
    }
    {
      us8 a = ldg8(P1 + (size_t)n * 1536 + 512 + col);
      us8 bb = ldg8(P1 + (size_t)(512 + n) * 1536 + 512 + col);
      us8 o8;
#pragma unroll
      for (int e = 0; e < 8; ++e) o8[e] = f2bf(xv * bf2f(a[e]) + bf2f(bb[e]));
      *reinterpret_cast<us8*>(k + ((size_t)(bh * 512 + n)) * 64 + oct * 8) = o8;
    }
  }
  // vT: row dh = r8 (col j = h*64+r8), n-chunks
  int j = h * 64 + r8;
  const unsigned short* av = vpre + (size_t)j * 512;
  const unsigned short* bv2 = vpre + 262144 + (size_t)j * 512;
  for (int i = 0; i < 8; ++i) {
    int n0 = i * 64 + oct * 8;
    us8 a = ldg8(av + n0);
    us8 bb = ldg8(bv2 + n0);
    f32x4 x0 = *reinterpret_cast<const f32x4*>(x + b * 512 + n0);
    f32x4 x1 = *reinterpret_cast<const f32x4*>(x + b * 512 + n0 + 4);
    us8 o8;
#pragma unroll
    for (int e = 0; e < 8; ++e) {
      float xe = (e < 4) ? x0[e] : x1[e - 4];
      o8[e] = f2bf(xe * bf2f(a[e]) + bf2f(bb[e]));
    }
    *reinterpret_cast<us8*>(vT + ((size_t)(bh * 64 + r8)) * 512 + n0) = o8;
  }
}

// ---------------- flash attention (round-6 structure, unchanged) ----------------
__global__ __launch_bounds__(512, 4) void k_attn(
    const unsigned short* __restrict__ q, const unsigned short* __restrict__ kk,
    const unsigned short* __restrict__ vT, unsigned short* __restrict__ o) {
  __shared__ __align__(16) unsigned short kbuf[2][4096];
  __shared__ __align__(16) unsigned short vbuf[2][4096];
  __shared__ __align__(16) unsigned short pbuf[8][1024];
  int bh = blockIdx.x >> 1, half = blockIdx.x & 1;
  int b = bh >> 3, h = bh & 7;
  const unsigned short* qh = q  + (size_t)bh * (N_ * DH_);
  const unsigned short* kh = kk + (size_t)bh * (N_ * DH_);
  const unsigned short* vh = vT + (size_t)bh * (DH_ * N_);
  int w = threadIdx.x >> 6, lane = threadIdx.x & 63;
  int lr = lane & 15, g = lane >> 4;
  const float cexp = 0.18033688011112042f;   // log2(e)/8
  const float THRraw = 44.35f;               // 8 / cexp

  us8 bq[2][2];
#pragma unroll
  for (int tt = 0; tt < 2; ++tt) {
    const unsigned short* qrow = qh + (size_t)(half * 256 + w * 32 + tt * 16 + lr) * DH_;
    bq[tt][0] = ldg8(qrow + g * 8);
    bq[tt][1] = ldg8(qrow + 32 + g * 8);
  }

  f32x4 oacc[2][4];
#pragma unroll
  for (int tt = 0; tt < 2; ++tt)
#pragma unroll
    for (int db = 0; db < 4; ++db) oacc[tt][db] = (f32x4){0.f, 0.f, 0.f, 0.f};
  float mrun[2] = {-3.0e38f, -3.0e38f};
  float lrun[2] = {0.f, 0.f};

  int k_mcl = w >> 1, k_kk = w & 1;
  const unsigned short* ksrc_base = kh + (size_t)(k_mcl * 16 + lr) * DH_ + k_kk * 32 + g * 8;
  const unsigned short* vsrc_base = vh + (size_t)(k_mcl * 16 + lr) * N_  + k_kk * 32 + g * 8;

  gload16(ksrc_base, &kbuf[0][w * 512]);
  gload16(vsrc_base, &vbuf[0][w * 512]);

  char* pw = (char*)&pbuf[w][0];

  for (int mb8 = 0; mb8 < 8; ++mb8) {
    int cur = mb8 & 1;
    if (mb8 < 7) {
      gload16(ksrc_base + (size_t)(mb8 + 1) * 64 * DH_, &kbuf[cur ^ 1][w * 512]);
      gload16(vsrc_base + (mb8 + 1) * 64,               &vbuf[cur ^ 1][w * 512]);
      asm volatile("s_waitcnt vmcnt(2)" ::: "memory");
    } else {
      asm volatile("s_waitcnt vmcnt(0)" ::: "memory");
    }
    __builtin_amdgcn_sched_barrier(0);
    __builtin_amdgcn_s_barrier();
    __builtin_amdgcn_sched_barrier(0);

    const char* kb = (const char*)&kbuf[cur][0];
    const char* vb = (const char*)&vbuf[cur][0];

#pragma unroll
    for (int tt = 0; tt < 2; ++tt) {
      f32x4 s[4];
#pragma unroll
      for (int mc_l = 0; mc_l < 4; ++mc_l) {
        f32x4 a = (f32x4){0.f, 0.f, 0.f, 0.f};
        a = mfma_bf16(*(const us8*)(kb + (mc_l * 2 + 0) * 1024 + lane * 16), bq[tt][0], a);
        a = mfma_bf16(*(const us8*)(kb + (mc_l * 2 + 1) * 1024 + lane * 16), bq[tt][1], a);
        s[mc_l] = a;
      }
      float pmax = fmaxf(fmaxf(s[0][0], s[0][1]), fmaxf(s[0][2], s[0][3]));
#pragma unroll
      for (int mc_l = 1; mc_l < 4; ++mc_l)
        pmax = fmaxf(pmax, fmaxf(fmaxf(s[mc_l][0], s[mc_l][1]), fmaxf(s[mc_l][2], s[mc_l][3])));
      pmax = fmaxf(pmax, __shfl_xor(pmax, 16, 64));
      pmax = fmaxf(pmax, __shfl_xor(pmax, 32, 64));
      if (__any(pmax > mrun[tt] + THRraw)) {   // defer-max (T13)
        float mnew = fmaxf(mrun[tt], pmax);
        float rs = fexp2((mrun[tt] - mnew) * cexp);
        mrun[tt] = mnew;
        lrun[tt] *= rs;
#pragma unroll
        for (int db = 0; db < 4; ++db) oacc[tt][db] *= rs;
      }
      float mcur = mrun[tt];
      float lsum = 0.f;
#pragma unroll
      for (int mc_l = 0; mc_l < 4; ++mc_l) {
#pragma unroll
        for (int r = 0; r < 4; ++r) {
          float p = fexp2((s[mc_l][r] - mcur) * cexp);
          s[mc_l][r] = p;
          lsum += p;
        }
      }
      lsum += __shfl_xor(lsum, 16, 64);
      lsum += __shfl_xor(lsum, 32, 64);
      lrun[tt] += lsum;
#pragma unroll
      for (int mc_l = 0; mc_l < 4; ++mc_l) {
        uint2 u;
        u.x = (unsigned)f2bf(s[mc_l][0]) | ((unsigned)f2bf(s[mc_l][1]) << 16);
        u.y = (unsigned)f2bf(s[mc_l][2]) | ((unsigned)f2bf(s[mc_l][3]) << 16);
        unsigned off = (unsigned)((mc_l >> 1) * 1024 + (((mc_l & 1) << 1) | (g >> 1)) * 256
                                  + lr * 16 + (g & 1) * 8);
        *reinterpret_cast<uint2*>(pw + off) = u;
      }
#pragma unroll
      for (int ks = 0; ks < 2; ++ks) {
        us8 bp = *(const us8*)(pw + ks * 1024 + lane * 16);
#pragma unroll
        for (int db = 0; db < 4; ++db) {
          us8 av = *(const us8*)(vb + (db * 2 + ks) * 1024 + lane * 16);
          oacc[tt][db] = mfma_bf16(av, bp, oacc[tt][db]);
        }
      }
    }
    if (mb8 < 7) {
      __builtin_amdgcn_sched_barrier(0);
      __builtin_amdgcn_s_barrier();
    }
  }

#pragma unroll
  for (int tt = 0; tt < 2; ++tt) {
    float inv = 1.f / lrun[tt];
#pragma unroll
    for (int db = 0; db < 4; ++db) {
      uint2 u;
      u.x = (unsigned)f2bf(oacc[tt][db][0] * inv) | ((unsigned)f2bf(oacc[tt][db][1] * inv) << 16);
      u.y = (unsigned)f2bf(oacc[tt][db][2] * inv) | ((unsigned)f2bf(oacc[tt][db][3] * inv) << 16);
      unsigned off = (unsigned)(lr * 128 + ((db * 32 + g * 8) ^ ((lr & 7) << 4)));
      *reinterpret_cast<uint2*>(pw + off) = u;
    }
    int n_l = lane >> 2;
#pragma unroll
    for (int hh = 0; hh < 2; ++hh) {
      int c16 = (lane & 3) + 4 * hh;
      us8 vv = *(const us8*)(pw + n_l * 128 + ((c16 ^ (n_l & 7)) << 4));
      *reinterpret_cast<us8*>(o + ((size_t)(b * 512 + half * 256 + w * 32 + tt * 16 + n_l)) * D_
                               + h * 64 + c16 * 8) = vv;
    }
  }
}

// ---------------- unembed row-dot: x_atten[m] = dot(o[m], wEff[n]) + cb[n] ----------------
__global__ __launch_bounds__(256) void k_undot(
    const unsigned short* __restrict__ o, const unsigned short* __restrict__ wEff,
    const float* __restrict__ cb, float* __restrict__ out_xa,
    unsigned short* __restrict__ xabf) {
  int m = blockIdx.x * 4 + (threadIdx.x >> 6);
  int lane = threadIdx.x & 63;
  int n = m & 511;
  us8 ov = ldg8(o + (size_t)m * 512 + lane * 8);
  us8 wv = ldg8(wEff + (size_t)n * 512 + lane * 8);
  float s = 0.f;
#pragma unroll
  for (int e = 0; e < 8; ++e) s += bf2f(ov[e]) * bf2f(wv[e]);
#pragma unroll
  for (int off = 32; off; off >>= 1) s += __shfl_xor(s, off, 64);
  if (lane == 0) {
    float v = s + cb[n];
    out_xa[m] = v;
    xabf[m] = f2bf(v);
  }
}

// ---------------- small M=32 MFMA GEMM for ff layers ----------------
__global__ __launch_bounds__(256) void k_ffmm(
    const unsigned short* __restrict__ A,
    const unsigned short* __restrict__ Bt,
    const float* __restrict__ bias, int K, int N, int outbf,
    unsigned short* __restrict__ obf, float* __restrict__ of) {
  int wave = threadIdx.x >> 6, lane = threadIdx.x & 63;
  int lrow = lane & 15, g = lane >> 4;
  int j = blockIdx.x * 64 + wave * 16 + lrow;
  f32x4 acc0 = (f32x4){0.f, 0.f, 0.f, 0.f}, acc1 = acc0;
  const unsigned short* brow = Bt + (size_t)j * K;
  for (int k0 = g * 8; k0 < K; k0 += 32) {
    us8 bfr = ldg8(brow + k0);
    acc0 = mfma_bf16(ldg8(A + (size_t)lrow * K + k0), bfr, acc0);
    acc1 = mfma_bf16(ldg8(A + (size_t)(16 + lrow) * K + k0), bfr, acc1);
  }
  float bj = bias[j];
#pragma unroll
  for (int r = 0; r < 4; ++r) {
    int mA = g * 4 + r, mB = 16 + g * 4 + r;
    float vA = acc0[r] + bj, vB = acc1[r] + bj;
    if (outbf) {
      obf[(size_t)mA * N + j] = f2bf(vA);
      obf[(size_t)mB * N + j] = f2bf(vB);
    } else {
      of[(size_t)mA * N + j] = vA;
      of[(size_t)mB * N + j] = vB;
    }
  }
}

// ---------------- bilinear upsample + min-max norm ----------------
__global__ __launch_bounds__(256) void k_up(
    const float* __restrict__ y3g, float* __restrict__ out) {
  __shared__ float y3[256];
  __shared__ float red[8];
  int b = blockIdx.x, t = threadIdx.x;
  y3[t] = y3g[(size_t)b * 256 + t];
  __syncthreads();
  float vals[4];
  float mn = 3.0e38f, mx = -3.0e38f;
#pragma unroll
  for (int p2 = 0; p2 < 4; ++p2) {
    int p = t * 4 + p2;
    int i = p >> 6, jj = p & 63;
    float sy = fmaxf((float)i * 0.5f - 0.25f, 0.0f);
    int y0 = (int)sy; float fy = sy - (float)y0;
    int y1i = min(y0 + 1, 7);
    float sx = fmaxf((float)jj * 0.5f - 0.25f, 0.0f);
    int x0 = (int)sx; float fx = sx - (float)x0;
    int x1 = min(x0 + 1, 31);
    float v00 = y3[y0 * 32 + x0], v01 = y3[y0 * 32 + x1];
    float v10 = y3[y1i * 32 + x0], v11 = y3[y1i * 32 + x1];
    float v = (1.f - fy) * ((1.f - fx) * v00 + fx * v01)
            +        fy  * ((1.f - fx) * v10 + fx * v11);
    vals[p2] = v;
    mn = fminf(mn, v); mx = fmaxf(mx, v);
  }
#pragma unroll
  for (int off = 32; off; off >>= 1) {
    mn = fminf(mn, __shfl_xor(mn, off, 64));
    mx = fmaxf(mx, __shfl_xor(mx, off, 64));
  }
  int wv = t >> 6;
  if ((t & 63) == 0) { red[wv] = mn; red[4 + wv] = mx; }
  __syncthreads();
  mn = fminf(fminf(red[0], red[1]), fminf(red[2], red[3]));
  mx = fmaxf(fmaxf(red[4], red[5]), fmaxf(red[6], red[7]));
  float inv = 1.f / (mx - mn + 1e-8f);
#pragma unroll
  for (int p2 = 0; p2 < 4; ++p2)
    out[(size_t)b * 1024 + t * 4 + p2] = (vals[p2] - mn) * inv;
}

// ---------------- launch ----------------
extern "C" void kernel_launch(void* const* d_in, const int* in_sizes, int n_in,
                              void* d_out, int out_size, void* d_ws, size_t ws_size,
                              hipStream_t stream) {
  const float* x     = (const float*)d_in[0];
  const float* W_emb = (const float*)d_in[1];
  const float* b_emb = (const float*)d_in[2];
  const float* Wq    = (const float*)d_in[3];
  const float* bq    = (const float*)d_in[4];
  const float* Wk    = (const float*)d_in[5];
  const float* bk    = (const float*)d_in[6];
  const float* Wv    = (const float*)d_in[7];
  const float* bv    = (const float*)d_in[8];
  const float* Wo    = (const float*)d_in[9];
  const float* bo    = (const float*)d_in[10];
  const float* W_un  = (const float*)d_in[11];
  const float* b_un  = (const float*)d_in[12];
  const float* W1    = (const float*)d_in[13];
  const float* b1    = (const float*)d_in[14];
  const float* W2    = (const float*)d_in[15];
  const float* b2    = (const float*)d_in[16];
  const float* W3    = (const float*)d_in[17];
  const float* b3    = (const float*)d_in[18];

  char* ws = (char*)d_ws;
  // obuf region [0,16M): pre-attn scratch P0/P1/vpre/WunBf/WoBf; attn overwrites with o.
  unsigned short* obuf  = (unsigned short*)(ws + 0);
  unsigned short* P0    = (unsigned short*)(ws + 0);          // 1 MB
  unsigned short* P1    = (unsigned short*)(ws + 1048576);    // 3 MB
  unsigned short* vpre  = (unsigned short*)(ws + 4194304);    // 1 MB
  unsigned short* WunBf = (unsigned short*)(ws + 5242880);    // 0.5 MB
  unsigned short* WoBf  = (unsigned short*)(ws + 5767168);    // 0.5 MB
  unsigned short* q     = (unsigned short*)(ws + 16777216);
  unsigned short* k     = (unsigned short*)(ws + 33554432);
  unsigned short* vT    = (unsigned short*)(ws + 50331648);
  unsigned short* wT    = (unsigned short*)(ws + 67108864);   // 1.5 MB (Wq^T,Wk^T,Wv^T)
  unsigned short* wEff  = (unsigned short*)(ws + 68681728);   // 0.5 MB
  float*          cb    = (float*)(ws + 69206016);            // 2 KB

  unsigned short* xabf = (unsigned short*)(ws + 16777216 + 65536);   // in dead q
  float*          y3   = (float*)(ws + 16777216 + 98304);            // in dead q
  unsigned short* w1T  = (unsigned short*)(ws + 33554432);           // in dead k
  unsigned short* w2T  = (unsigned short*)(ws + 35651584);
  unsigned short* w3T  = (unsigned short*)(ws + 37748736);
  unsigned short* y1bf = (unsigned short*)(ws + 38010880);
  unsigned short* y2bf = (unsigned short*)(ws + 38141952);

  float* out_y  = (float*)d_out;            // [32,1,16,64]
  float* out_xa = ((float*)d_out) + 32768;  // [32,512,1]

  k_cast<<<dim3(1024), dim3(256), 0, stream>>>(W_emb, b_emb, W_un, Wo, P0, WunBf, WoBf);
  k_transpose3<<<dim3(16, 16, 3), dim3(32, 8), 0, stream>>>(Wq, Wk, Wv, wT);

  k_prep<<<dim3(112), dim3(256), 0, stream>>>(
      P0, wT, WunBf, WoBf, bq, bk, bv, P1, vpre, wEff);
  k_cb<<<dim3(128), dim3(256), 0, stream>>>(W_un, bo, b_un, cb);

  k_qkvgen<<<dim3(256), dim3(512), 0, stream>>>(x, P1, vpre, q, k, vT);

  k_attn<<<dim3(512), dim3(512), 0, stream>>>(q, k, vT, obuf);

  k_undot<<<dim3(4096), dim3(256), 0, stream>>>(obuf, wEff, cb, out_xa, xabf);

  k_transpose<<<dim3(64, 16), dim3(32, 8), 0, stream>>>(W1, w1T, 512, 2048);
  k_transpose<<<dim3(16, 64), dim3(32, 8), 0, stream>>>(W2, w2T, 2048, 512);
  k_transpose<<<dim3(8, 16),  dim3(32, 8), 0, stream>>>(W3, w3T, 512, 256);

  k_ffmm<<<dim3(32), dim3(256), 0, stream>>>(xabf, w1T, b1, 512, 2048, 1, y1bf, nullptr);
  k_ffmm<<<dim3(8),  dim3(256), 0, stream>>>(y1bf, w2T, b2, 2048, 512, 1, y2bf, nullptr);
  k_ffmm<<<dim3(4),  dim3(256), 0, stream>>>(y2bf, w3T, b3, 512, 256, 0, nullptr, y3);

  k_up<<<dim3(B_), dim3(256), 0, stream>>>(y3, out_y);
}